// Round 13
// baseline (189.030 us; speedup 1.0000x reference)
//
#include <hip/hip_runtime.h>
#include <stdint.h>

typedef unsigned short u16;
typedef __attribute__((ext_vector_type(8))) __bf16 bf16x8;
typedef __attribute__((ext_vector_type(8))) short short8;
typedef __attribute__((ext_vector_type(4))) float f32x4;
typedef __attribute__((ext_vector_type(16))) float f32x16;
typedef __attribute__((ext_vector_type(4))) uint32_t u32x4;

#define AS1 __attribute__((address_space(1)))
#define AS3 __attribute__((address_space(3)))

__device__ __forceinline__ void load_lds16(const void* g, void* l) {
    __builtin_amdgcn_global_load_lds((AS1 void*)g, (AS3 void*)l, 16, 0, 0);
}

__device__ __forceinline__ u16 f2bf(float f) {
    uint32_t u = __builtin_bit_cast(uint32_t, f);
    u += 0x7FFFu + ((u >> 16) & 1u);
    return (u16)(u >> 16);
}

__device__ __forceinline__ f32x4 mfma16(bf16x8 a, bf16x8 b, f32x4 c) {
    return __builtin_amdgcn_mfma_f32_16x16x32_bf16(a, b, c, 0, 0, 0);
}
__device__ __forceinline__ f32x16 mfma32(bf16x8 a, bf16x8 b, f32x16 c) {
    return __builtin_amdgcn_mfma_f32_32x32x16_bf16(a, b, c, 0, 0, 0);
}

__device__ __forceinline__ float rcpf(float x) {
    float r;
    asm("v_rcp_f32 %0, %1" : "=v"(r) : "v"(x));
    return r;
}

#define CLOG 0.18033688f   /* 0.125 * log2(e) -- folded into Q at qkv epilogue */

// ---------------------------------------------------------------- fused cast f32->bf16
__global__ __launch_bounds__(256) void cast_all(const float* __restrict__ x,
                                                const float* __restrict__ wq,
                                                const float* __restrict__ wk,
                                                const float* __restrict__ wv,
                                                const float* __restrict__ wp,
                                                u16* __restrict__ xb,
                                                u16* __restrict__ wqkv,
                                                u16* __restrict__ wpb) {
    const int bid = blockIdx.x;
    const float* src;
    u16* dst;
    int boff;
    if (bid < 8192)       { src = x;  dst = xb;             boff = bid; }
    else if (bid < 9216)  { src = wq; dst = wqkv;           boff = bid - 8192; }
    else if (bid < 10240) { src = wk; dst = wqkv + 1048576; boff = bid - 9216; }
    else if (bid < 11264) { src = wv; dst = wqkv + 2097152; boff = bid - 10240; }
    else                  { src = wp; dst = wpb;            boff = bid - 11264; }
    const int i = (boff * 256 + threadIdx.x) * 4;
    const float4 v = *(const float4*)(src + i);
    u16 o0 = f2bf(v.x), o1 = f2bf(v.y), o2 = f2bf(v.z), o3 = f2bf(v.w);
    uint32_t lo = (uint32_t)o0 | ((uint32_t)o1 << 16);
    uint32_t hi = (uint32_t)o2 | ((uint32_t)o3 << 16);
    uint2 p; p.x = lo; p.y = hi;
    *(uint2*)(dst + i) = p;
}

// ---------------------------------------------------------------- 128x128 GEMM core (proj)
template<int KDIM>
__device__ __forceinline__ void gemm_core(const u16* __restrict__ A, const u16* __restrict__ Bw,
                                          int m0, int n0, char* lds, f32x4 acc[4][4]) {
    const int tid = threadIdx.x;
    const int w = tid >> 6, l = tid & 63;
    const int lg = l >> 4, lc = l & 15;
    const int wm = (w >> 1) * 64, wn = (w & 1) * 64;
    char* As = lds;
    char* Bs = lds + 16384;
    for (int kt = 0; kt < KDIM; kt += 64) {
#pragma unroll
        for (int i = 0; i < 4; ++i) {
            const int e = i * 256 + tid;
            const int row = e >> 3, c = e & 7;
            const int cs = c ^ (row & 7);
            load_lds16(A + (size_t)(m0 + row) * KDIM + kt + cs * 8, As + i * 4096 + w * 1024);
            load_lds16(Bw + (size_t)(n0 + row) * KDIM + kt + cs * 8, Bs + i * 4096 + w * 1024);
        }
        __syncthreads();
#pragma unroll
        for (int kk = 0; kk < 2; ++kk) {
            bf16x8 af[4], bfr[4];
            const int byo = kk * 64 + lg * 16;
#pragma unroll
            for (int mi = 0; mi < 4; ++mi) {
                const int row = wm + mi * 16 + lc;
                af[mi] = *(const bf16x8*)(As + row * 128 + (byo ^ ((row & 7) << 4)));
            }
#pragma unroll
            for (int ni = 0; ni < 4; ++ni) {
                const int row = wn + ni * 16 + lc;
                bfr[ni] = *(const bf16x8*)(Bs + row * 128 + (byo ^ ((row & 7) << 4)));
            }
#pragma unroll
            for (int mi = 0; mi < 4; ++mi)
#pragma unroll
                for (int ni = 0; ni < 4; ++ni)
                    acc[mi][ni] = mfma16(af[mi], bfr[ni], acc[mi][ni]);
        }
        __syncthreads();
    }
}

// ---------------------------------------------------------------- fused QKV projection
// r12 8-phase 256x256 (kept: passed, not regressed). See r12 comments.
__global__ __launch_bounds__(512) __attribute__((amdgpu_waves_per_eu(2, 2)))
void qkv_gemm(const u16* __restrict__ xb, const u16* __restrict__ wqkv,
              const float* __restrict__ bq, const float* __restrict__ bk,
              const float* __restrict__ bv,
              u16* __restrict__ qo, u16* __restrict__ ko, u16* __restrict__ vt) {
    __shared__ char lds[131072];
    const int tid = threadIdx.x;
    const int w = tid >> 6, l = tid & 63;
    const int lg = l >> 4, lc = l & 15;
    const int wr = w >> 2, wc = w & 3;
    const int id = blockIdx.x;
    const int xcd = id & 7, sl = id >> 3;
    const int nIdx = sl >> 2, mloc = sl & 3;
    const int m0 = (xcd * 4 + mloc) * 256;
    const int n0 = nIdx * 256;

    f32x4 acc[8][4] = {};

#define STAGE_A(H, KT, BUFP)                                                                     \
    {                                                                                            \
        _Pragma("unroll")                                                                        \
        for (int i_ = 0; i_ < 2; ++i_) {                                                         \
            const int e_ = i_ * 512 + tid;                                                       \
            const int row_ = e_ >> 3, c_ = e_ & 7;                                               \
            const int cs_ = c_ ^ (row_ & 7);                                                     \
            load_lds16(xb + (size_t)(m0 + (H) * 128 + row_) * 1024 + (KT) + cs_ * 8,             \
                       (BUFP) + (H) * 16384 + i_ * 8192 + w * 1024);                             \
        }                                                                                        \
    }
#define STAGE_B(H, KT, BUFP)                                                                     \
    {                                                                                            \
        _Pragma("unroll")                                                                        \
        for (int i_ = 0; i_ < 2; ++i_) {                                                         \
            const int e_ = i_ * 512 + tid;                                                       \
            const int row_ = e_ >> 3, c_ = e_ & 7;                                               \
            const int cs_ = c_ ^ (row_ & 7);                                                     \
            load_lds16(wqkv + (size_t)(n0 + (H) * 128 + row_) * 1024 + (KT) + cs_ * 8,           \
                       (BUFP) + 32768 + (H) * 16384 + i_ * 8192 + w * 1024);                     \
        }                                                                                        \
    }
#define PHASE_BARRIER()                                                                          \
    {                                                                                            \
        __builtin_amdgcn_sched_barrier(0);                                                       \
        __builtin_amdgcn_s_barrier();                                                            \
    }

    STAGE_A(0, 0, lds) STAGE_A(1, 0, lds)
    STAGE_B(0, 0, lds) STAGE_B(1, 0, lds)
    STAGE_B(0, 64, lds + 65536) STAGE_B(1, 64, lds + 65536)
    asm volatile("s_waitcnt vmcnt(4)" ::: "memory");
    PHASE_BARRIER()

    for (int u = 0; u < 16; ++u) {
        const int kt = u * 64;
        char* cb = lds + (u & 1) * 65536;
        char* nb = lds + ((u + 1) & 1) * 65536;
        char* abase = cb + wr * 16384;
        char* bbase = cb + 32768 + (wc >> 1) * 16384;
        const int brl = (wc & 1) * 64;
        bf16x8 af[4][2], bfr[4][2];
#pragma unroll
        for (int m = 0; m < 4; ++m) {
            const int row = m * 16 + lc;
#pragma unroll
            for (int kk = 0; kk < 2; ++kk)
                af[m][kk] = *(const bf16x8*)(abase + row * 128 + ((kk * 64 + lg * 16) ^ ((row & 7) << 4)));
        }
#pragma unroll
        for (int n = 0; n < 2; ++n) {
            const int row = brl + n * 16 + lc;
#pragma unroll
            for (int kk = 0; kk < 2; ++kk)
                bfr[n][kk] = *(const bf16x8*)(bbase + row * 128 + ((kk * 64 + lg * 16) ^ ((row & 7) << 4)));
        }
        if (u < 15) STAGE_A(0, kt + 64, nb)
        PHASE_BARRIER()
        __builtin_amdgcn_s_setprio(1);
#pragma unroll
        for (int m = 0; m < 4; ++m)
#pragma unroll
            for (int n = 0; n < 2; ++n)
#pragma unroll
                for (int kk = 0; kk < 2; ++kk)
                    acc[m][n] = mfma16(af[m][kk], bfr[n][kk], acc[m][n]);
        __builtin_amdgcn_s_setprio(0);
        PHASE_BARRIER()
#pragma unroll
        for (int n = 2; n < 4; ++n) {
            const int row = brl + n * 16 + lc;
#pragma unroll
            for (int kk = 0; kk < 2; ++kk)
                bfr[n][kk] = *(const bf16x8*)(bbase + row * 128 + ((kk * 64 + lg * 16) ^ ((row & 7) << 4)));
        }
        if (u < 15) STAGE_A(1, kt + 64, nb)
        PHASE_BARRIER()
        __builtin_amdgcn_s_setprio(1);
#pragma unroll
        for (int m = 0; m < 4; ++m)
#pragma unroll
            for (int n = 2; n < 4; ++n)
#pragma unroll
                for (int kk = 0; kk < 2; ++kk)
                    acc[m][n] = mfma16(af[m][kk], bfr[n][kk], acc[m][n]);
        __builtin_amdgcn_s_setprio(0);
        PHASE_BARRIER()
#pragma unroll
        for (int m = 0; m < 4; ++m) {
            const int row = 64 + m * 16 + lc;
#pragma unroll
            for (int kk = 0; kk < 2; ++kk)
                af[m][kk] = *(const bf16x8*)(abase + row * 128 + ((kk * 64 + lg * 16) ^ ((row & 7) << 4)));
        }
        if (u < 14) STAGE_B(0, kt + 128, cb)
        PHASE_BARRIER()
        __builtin_amdgcn_s_setprio(1);
#pragma unroll
        for (int m = 0; m < 4; ++m)
#pragma unroll
            for (int n = 0; n < 2; ++n)
#pragma unroll
                for (int kk = 0; kk < 2; ++kk)
                    acc[4 + m][n] = mfma16(af[m][kk], bfr[n][kk], acc[4 + m][n]);
        __builtin_amdgcn_s_setprio(0);
        PHASE_BARRIER()
        if (u < 14) STAGE_B(1, kt + 128, cb)
        PHASE_BARRIER()
        __builtin_amdgcn_s_setprio(1);
#pragma unroll
        for (int m = 0; m < 4; ++m)
#pragma unroll
            for (int n = 2; n < 4; ++n)
#pragma unroll
                for (int kk = 0; kk < 2; ++kk)
                    acc[4 + m][n] = mfma16(af[m][kk], bfr[n][kk], acc[4 + m][n]);
        __builtin_amdgcn_s_setprio(0);
        if (u >= 14) { asm volatile("s_waitcnt vmcnt(0)" ::: "memory"); }
        else         { asm volatile("s_waitcnt vmcnt(4)" ::: "memory"); }
        PHASE_BARRIER()
    }

    const int ngw = n0 + wc * 64;
    const int whichw = ngw >> 10;
    const float* bias = whichw == 0 ? bq : (whichw == 1 ? bk : bv);
    if (whichw == 2) {
#pragma unroll
        for (int mi = 0; mi < 8; ++mi)
#pragma unroll
            for (int ni = 0; ni < 4; ++ni) {
                const int ng = ngw + ni * 16 + lc;
                const int c = ng & 1023;
                const int h = c >> 6, d = c & 63;
                const float bb = bias[c];
                const int t0 = m0 + wr * 128 + mi * 16 + lg * 4;
                const int b = t0 >> 11, t = t0 & 2047;
                uint32_t w0 = (uint32_t)f2bf(acc[mi][ni][0] + bb) | ((uint32_t)f2bf(acc[mi][ni][1] + bb) << 16);
                uint32_t w1 = (uint32_t)f2bf(acc[mi][ni][2] + bb) | ((uint32_t)f2bf(acc[mi][ni][3] + bb) << 16);
                uint2 pk; pk.x = w0; pk.y = w1;
                *(uint2*)(vt + (((size_t)(b * 16 + h)) * 64 + d) * 2048 + t) = pk;
            }
    } else {
        u16* outb = whichw == 0 ? qo : ko;
        const float sc = whichw == 0 ? CLOG : 1.0f;
#pragma unroll
        for (int mi = 0; mi < 8; ++mi)
#pragma unroll
            for (int ni = 0; ni < 4; ++ni)
#pragma unroll
                for (int r = 0; r < 4; ++r) {
                    const int m = m0 + wr * 128 + mi * 16 + lg * 4 + r;
                    const int ng = ngw + ni * 16 + lc;
                    const int c = ng & 1023;
                    const float v = (acc[mi][ni][r] + bias[c]) * sc;
                    const int h = c >> 6, d = c & 63;
                    const int b = m >> 11, t = m & 2047;
                    outb[(((size_t)(b * 16 + h)) * 2048 + t) * 64 + d] = f2bf(v);
                }
    }
}

// ---------------------------------------------------------------- flash attention (causal)
// r13: WAVE-WIDENING -- each wave owns 64 q-rows (two 32-q groups g0/g1).
// The shared K-frag (akf) and V-frag (bvf) LDS reads feed BOTH groups' MFMAs:
// LDS reads per MFMA 1.0 -> 0.5 (the saturated pipe: 4.26M conflicts invariant
// across r0-r12, MfmaUtil 18%). Staging tiles/head 200 -> 144. Block = 4 waves
// x 64 rows = 256 q-rows; 512 blocks, 2/CU co-resident (all resident at t=0),
// CU pairs (s',7-s') sum to 36 rounds. waves_per_eu(2,2): 256-VGPR budget for
// the ~200-reg live set (oacc 64 + aqf 32 + sf 64 + wv 16 + addr).
// Max-free softmax (r10), Q pre-scaled by CLOG (r12).
__global__ __launch_bounds__(256) __attribute__((amdgpu_waves_per_eu(2, 2)))
void attn_kernel(const u16* __restrict__ qbuf, const u16* __restrict__ kbuf,
                 const u16* __restrict__ vtb, u16* __restrict__ attb) {
    __shared__ char lds[32768];  // [parity][ K 8KB | Vt 8KB ]
    const int tid = threadIdx.x;
    const int w = tid >> 6, l = tid & 63;        // w 0..3
    const int l31 = l & 31, hi = l >> 5;
    const int id = blockIdx.x;
    const int xcd = id & 7, slot = id >> 3;      // slot 0..63 per XCD
    const int round = slot >> 5, k5 = slot & 31;
    const int sp = round ? (7 - (k5 & 7)) : (k5 & 7);  // CU pair (sp,7-sp)
    const int bh = xcd * 8 + round * 4 + (k5 >> 3);    // 8 heads/XCD
    const size_t base = (size_t)bh * 2048 * 64;
    const int qb0 = sp * 256 + w * 64;           // wave's 64 q rows
    const int qw00 = qb0, qw01 = qb0 + 32;       // the two 32-q groups
    const int jmax = qb0 >> 6;                   // same for both groups
    const int tH = 4 * sp + 4;                   // tiles staged by the block
    const int qg0 = qw00 + l31, qg1 = qw01 + l31;

    // Q B-fragments per group: lane holds q=qw0g+l31, d=16t+8hi+j
    bf16x8 aqf0[4], aqf1[4];
#pragma unroll
    for (int t = 0; t < 4; ++t) {
        aqf0[t] = *(const bf16x8*)(qbuf + base + (size_t)(qw00 + l31) * 64 + t * 16 + hi * 8);
        aqf1[t] = *(const bf16x8*)(qbuf + base + (size_t)(qw01 + l31) * 64 + t * 16 + hi * 8);
    }

    f32x16 oacc0[2], oacc1[2];
#pragma unroll
    for (int i = 0; i < 16; ++i) {
        oacc0[0][i] = 0.f; oacc0[1][i] = 0.f;
        oacc1[0][i] = 0.f; oacc1[1][i] = 0.f;
    }
    float lrun0 = 0.f, lrun1 = 0.f;  // own-half sums, cross-half deferred

#define ISSUE_K(J, BUF)                                                                          \
    {                                                                                            \
        _Pragma("unroll")                                                                        \
        for (int i = 0; i < 2; ++i) {                                                            \
            const int e = i * 256 + tid;                                                         \
            const int row = e >> 3, c = e & 7;                                                   \
            const int cs = c ^ (row & 7);                                                        \
            load_lds16(kbuf + base + (size_t)((J) * 64 + row) * 64 + cs * 8,                     \
                       (BUF) + i * 4096 + w * 1024);                                             \
        }                                                                                        \
    }
#define ISSUE_VT(J, BUF)                                                                         \
    {                                                                                            \
        _Pragma("unroll")                                                                        \
        for (int i = 0; i < 2; ++i) {                                                            \
            const int e = i * 256 + tid;                                                         \
            const int row = e >> 3, c = e & 7;                                                   \
            const int cs = c ^ (row & 7);                                                        \
            load_lds16(vtb + base + (size_t)row * 2048 + (J) * 64 + cs * 8,                      \
                       (BUF) + i * 4096 + w * 1024);                                             \
        }                                                                                        \
    }

// max-free, pre-scaled: P = exp2(S); own-half pairwise sum; pack to bf16 pairs
#define SOFTMAX_PACK(SF, WV, LRUN)                                              \
    {                                                                           \
        float ps[8];                                                            \
        _Pragma("unroll")                                                       \
        for (int i = 0; i < 8; ++i) {                                           \
            const float p0 = exp2f((SF)[2 * i]);                                \
            const float p1 = exp2f((SF)[2 * i + 1]);                            \
            (SF)[2 * i] = p0;                                                   \
            (SF)[2 * i + 1] = p1;                                               \
            ps[i] = p0 + p1;                                                    \
        }                                                                       \
        (LRUN) += ((ps[0] + ps[1]) + (ps[2] + ps[3])) +                         \
                  ((ps[4] + ps[5]) + (ps[6] + ps[7]));                          \
        _Pragma("unroll")                                                       \
        for (int i = 0; i < 8; ++i) {                                           \
            uint32_t ww;                                                        \
            asm("v_cvt_pk_bf16_f32 %0, %1, %2"                                  \
                : "=v"(ww) : "v"((SF)[2 * i]), "v"((SF)[2 * i + 1]));           \
            (WV)[i] = ww;                                                       \
        }                                                                       \
    }

// P A-frag build from packed pairs (r0-verified shuffle/select)
#define BUILD_PAF(W, KL, PAF)                                                   \
    {                                                                           \
        const uint32_t wa = W[4 * (KL) + 0], wb_ = W[4 * (KL) + 1];             \
        const uint32_t wc = W[4 * (KL) + 2], wd = W[4 * (KL) + 3];              \
        const uint32_t xa = (uint32_t)__shfl_xor((int)wa, 32, 64);              \
        const uint32_t xb = (uint32_t)__shfl_xor((int)wb_, 32, 64);             \
        const uint32_t xc = (uint32_t)__shfl_xor((int)wc, 32, 64);              \
        const uint32_t xd = (uint32_t)__shfl_xor((int)wd, 32, 64);              \
        u32x4 pw;                                                               \
        pw[0] = hi ? xc : wa;                                                   \
        pw[1] = hi ? xd : wb_;                                                  \
        pw[2] = hi ? wc : xa;                                                   \
        pw[3] = hi ? wd : xb;                                                   \
        PAF = __builtin_bit_cast(bf16x8, pw);                                   \
    }

    ISSUE_K(0, lds);
    ISSUE_VT(0, lds + 8192);
    for (int j = 0; j < tH; ++j) {
        __syncthreads();   // drains tile-j loads (issued a full round earlier)
        if (j + 1 < tH) {
            char* nb2 = lds + ((j + 1) & 1) * 16384;
            ISSUE_K(j + 1, nb2);
            ISSUE_VT(j + 1, nb2 + 8192);
        }
        if (j <= jmax) {
            char* Ks = lds + (j & 1) * 16384;
            char* Vt = Ks + 8192;
#pragma unroll
            for (int b2 = 0; b2 < 2; ++b2) {
                const int S0b = j * 64 + b2 * 32;
                const bool act0 = (S0b <= qw00 + 31);    // false only at (j==jmax,b2==1)
                // ---- S^T = K Q^T: akf read ONCE, feeds both groups
                f32x16 sg0, sg1;
#pragma unroll
                for (int i = 0; i < 16; ++i) { sg0[i] = 0.f; sg1[i] = 0.f; }
                const int row = b2 * 32 + l31;
                __builtin_amdgcn_s_setprio(1);
#pragma unroll
                for (int t = 0; t < 4; ++t) {
                    const bf16x8 akf = *(const bf16x8*)(Ks + row * 128 + ((t * 32 + hi * 16) ^ ((row & 7) << 4)));
                    if (act0) sg0 = mfma32(akf, aqf0[t], sg0);
                    sg1 = mfma32(akf, aqf1[t], sg1);
                }
                __builtin_amdgcn_s_setprio(0);
                // ---- causal masks (fire only on the two diagonal sub-blocks)
                if (act0 && (S0b + 31 > qw00)) {
#pragma unroll
                    for (int rg = 0; rg < 16; ++rg) {
                        const int ss = S0b + (rg & 3) + 8 * (rg >> 2) + 4 * hi;
                        if (ss > qg0) sg0[rg] = -3.0e38f;
                    }
                }
                if (S0b + 31 > qw01) {
#pragma unroll
                    for (int rg = 0; rg < 16; ++rg) {
                        const int ss = S0b + (rg & 3) + 8 * (rg >> 2) + 4 * hi;
                        if (ss > qg1) sg1[rg] = -3.0e38f;
                    }
                }
                // ---- softmax + pack per group
                uint32_t wv0[8], wv1[8];
                if (act0) SOFTMAX_PACK(sg0, wv0, lrun0)
                SOFTMAX_PACK(sg1, wv1, lrun1)
                // ---- PV: bvf read ONCE per (kl,nb), feeds both groups
#pragma unroll
                for (int kl = 0; kl < 2; ++kl) {
                    bf16x8 paf0, paf1;
                    if (act0) BUILD_PAF(wv0, kl, paf0)
                    BUILD_PAF(wv1, kl, paf1)
                    const int ks = b2 * 2 + kl;
                    __builtin_amdgcn_s_setprio(1);
#pragma unroll
                    for (int nb = 0; nb < 2; ++nb) {
                        const int vrow = nb * 32 + l31;
                        const bf16x8 bvf = *(const bf16x8*)(Vt + vrow * 128 +
                            ((ks * 32 + hi * 16) ^ ((vrow & 7) << 4)));
                        if (act0) oacc0[nb] = mfma32(paf0, bvf, oacc0[nb]);
                        oacc1[nb] = mfma32(paf1, bvf, oacc1[nb]);
                    }
                    __builtin_amdgcn_s_setprio(0);
                }
            }
        }
    }
    // ---- epilogue per group: cross-half lrun, normalize (v_rcp), write (B,T,C)
    const int b = bh >> 4, h = bh & 15;
    {
        const float lf = lrun0 + __shfl_xor(lrun0, 32, 64);
        const float inv = rcpf(lf);
#pragma unroll
        for (int rq = 0; rq < 4; ++rq)
#pragma unroll
            for (int rr = 0; rr < 4; ++rr) {
                const int q = rr + 8 * rq + 4 * hi;
                const float iv = __shfl(inv, q | (l & 32), 64);
                const int t = qw00 + q;
#pragma unroll
                for (int nb = 0; nb < 2; ++nb) {
                    const int c = h * 64 + nb * 32 + l31;
                    attb[((size_t)(b * 2048 + t)) * 1024 + c] = f2bf(oacc0[nb][rq * 4 + rr] * iv);
                }
            }
    }
    {
        const float lf = lrun1 + __shfl_xor(lrun1, 32, 64);
        const float inv = rcpf(lf);
#pragma unroll
        for (int rq = 0; rq < 4; ++rq)
#pragma unroll
            for (int rr = 0; rr < 4; ++rr) {
                const int q = rr + 8 * rq + 4 * hi;
                const float iv = __shfl(inv, q | (l & 32), 64);
                const int t = qw01 + q;
#pragma unroll
                for (int nb = 0; nb < 2; ++nb) {
                    const int c = h * 64 + nb * 32 + l31;
                    attb[((size_t)(b * 2048 + t)) * 1024 + c] = f2bf(oacc1[nb][rq * 4 + rr] * iv);
                }
            }
    }
}

// ---------------------------------------------------------------- output projection (fp32 out)
__global__ __launch_bounds__(256) void proj_gemm(const u16* __restrict__ attb, const u16* __restrict__ wpb,
                                                 const float* __restrict__ bp, float* __restrict__ out) {
    __shared__ char lds[32768];
    f32x4 acc[4][4] = {};
    const int id = blockIdx.x;
    const int xcd = id & 7, sl = id >> 3;
    const int nIdx = sl >> 3, mloc = sl & 7;
    const int m0 = (xcd * 8 + mloc) * 128;
    const int n0 = nIdx * 128;
    gemm_core<1024>(attb, wpb, m0, n0, lds, acc);
    const int tid = threadIdx.x;
    const int w = tid >> 6, l = tid & 63;
    const int lg = l >> 4, lc = l & 15;
    const int wm = (w >> 1) * 64, wn = (w & 1) * 64;
#pragma unroll
    for (int mi = 0; mi < 4; ++mi)
#pragma unroll
        for (int ni = 0; ni < 4; ++ni)
#pragma unroll
            for (int r = 0; r < 4; ++r) {
                const int m = m0 + wm + mi * 16 + lg * 4 + r;
                const int n = n0 + wn + ni * 16 + lc;
                out[(size_t)m * 1024 + n] = acc[mi][ni][r] + bp[n];
            }
}

// ---------------------------------------------------------------- launch
extern "C" void kernel_launch(void* const* d_in, const int* in_sizes, int n_in,
                              void* d_out, int out_size, void* d_ws, size_t ws_size,
                              hipStream_t stream) {
    const float* x  = (const float*)d_in[0];
    const float* Wk = (const float*)d_in[1];
    const float* bk = (const float*)d_in[2];
    const float* Wq = (const float*)d_in[3];
    const float* bq = (const float*)d_in[4];
    const float* Wv = (const float*)d_in[5];
    const float* bv = (const float*)d_in[6];
    const float* Wp = (const float*)d_in[7];
    const float* bp = (const float*)d_in[8];
    char* ws = (char*)d_ws;
    u16* xb   = (u16*)(ws);
    u16* wqkv = (u16*)(ws + 16777216);
    u16* wpb  = (u16*)(ws + 23068672);
    u16* qbuf = (u16*)(ws + 25165824);
    u16* kbuf = (u16*)(ws + 41943040);
    u16* vtb  = (u16*)(ws + 58720256);   // (B,H,D,T) pre-transposed V
    u16* attb = (u16*)(ws + 75497472);

    cast_all<<<12288, 256, 0, stream>>>(x, Wq, Wk, Wv, Wp, xb, wqkv, wpb);
    qkv_gemm<<<384, 512, 0, stream>>>(xb, wqkv, bq, bk, bv, qbuf, kbuf, vtb);
    attn_kernel<<<512, 256, 0, stream>>>(qbuf, kbuf, vtb, attb);
    proj_gemm<<<512, 256, 0, stream>>>(attb, wpb, bp, (float*)d_out);
}

// Round 14
// 173.039 us; speedup vs baseline: 1.0924x; 1.0924x over previous
//
#include <hip/hip_runtime.h>
#include <stdint.h>

typedef unsigned short u16;
typedef __attribute__((ext_vector_type(8))) __bf16 bf16x8;
typedef __attribute__((ext_vector_type(8))) short short8;
typedef __attribute__((ext_vector_type(4))) float f32x4;
typedef __attribute__((ext_vector_type(16))) float f32x16;
typedef __attribute__((ext_vector_type(4))) uint32_t u32x4;

#define AS1 __attribute__((address_space(1)))
#define AS3 __attribute__((address_space(3)))

__device__ __forceinline__ void load_lds16(const void* g, void* l) {
    __builtin_amdgcn_global_load_lds((AS1 void*)g, (AS3 void*)l, 16, 0, 0);
}

__device__ __forceinline__ u16 f2bf(float f) {
    uint32_t u = __builtin_bit_cast(uint32_t, f);
    u += 0x7FFFu + ((u >> 16) & 1u);
    return (u16)(u >> 16);
}

__device__ __forceinline__ f32x4 mfma16(bf16x8 a, bf16x8 b, f32x4 c) {
    return __builtin_amdgcn_mfma_f32_16x16x32_bf16(a, b, c, 0, 0, 0);
}
__device__ __forceinline__ f32x16 mfma32(bf16x8 a, bf16x8 b, f32x16 c) {
    return __builtin_amdgcn_mfma_f32_32x32x16_bf16(a, b, c, 0, 0, 0);
}

__device__ __forceinline__ float rcpf(float x) {
    float r;
    asm("v_rcp_f32 %0, %1" : "=v"(r) : "v"(x));
    return r;
}

#define CLOG 0.18033688f   /* 0.125 * log2(e) -- folded into Q at qkv epilogue */

// ---------------------------------------------------------------- fused cast f32->bf16
__global__ __launch_bounds__(256) void cast_all(const float* __restrict__ x,
                                                const float* __restrict__ wq,
                                                const float* __restrict__ wk,
                                                const float* __restrict__ wv,
                                                const float* __restrict__ wp,
                                                u16* __restrict__ xb,
                                                u16* __restrict__ wqkv,
                                                u16* __restrict__ wpb) {
    const int bid = blockIdx.x;
    const float* src;
    u16* dst;
    int boff;
    if (bid < 8192)       { src = x;  dst = xb;             boff = bid; }
    else if (bid < 9216)  { src = wq; dst = wqkv;           boff = bid - 8192; }
    else if (bid < 10240) { src = wk; dst = wqkv + 1048576; boff = bid - 9216; }
    else if (bid < 11264) { src = wv; dst = wqkv + 2097152; boff = bid - 10240; }
    else                  { src = wp; dst = wpb;            boff = bid - 11264; }
    const int i = (boff * 256 + threadIdx.x) * 4;
    const float4 v = *(const float4*)(src + i);
    u16 o0 = f2bf(v.x), o1 = f2bf(v.y), o2 = f2bf(v.z), o3 = f2bf(v.w);
    uint32_t lo = (uint32_t)o0 | ((uint32_t)o1 << 16);
    uint32_t hi = (uint32_t)o2 | ((uint32_t)o3 << 16);
    uint2 p; p.x = lo; p.y = hi;
    *(uint2*)(dst + i) = p;
}

// ---------------------------------------------------------------- 128x128 GEMM core (proj)
template<int KDIM>
__device__ __forceinline__ void gemm_core(const u16* __restrict__ A, const u16* __restrict__ Bw,
                                          int m0, int n0, char* lds, f32x4 acc[4][4]) {
    const int tid = threadIdx.x;
    const int w = tid >> 6, l = tid & 63;
    const int lg = l >> 4, lc = l & 15;
    const int wm = (w >> 1) * 64, wn = (w & 1) * 64;
    char* As = lds;
    char* Bs = lds + 16384;
    for (int kt = 0; kt < KDIM; kt += 64) {
#pragma unroll
        for (int i = 0; i < 4; ++i) {
            const int e = i * 256 + tid;
            const int row = e >> 3, c = e & 7;
            const int cs = c ^ (row & 7);
            load_lds16(A + (size_t)(m0 + row) * KDIM + kt + cs * 8, As + i * 4096 + w * 1024);
            load_lds16(Bw + (size_t)(n0 + row) * KDIM + kt + cs * 8, Bs + i * 4096 + w * 1024);
        }
        __syncthreads();
#pragma unroll
        for (int kk = 0; kk < 2; ++kk) {
            bf16x8 af[4], bfr[4];
            const int byo = kk * 64 + lg * 16;
#pragma unroll
            for (int mi = 0; mi < 4; ++mi) {
                const int row = wm + mi * 16 + lc;
                af[mi] = *(const bf16x8*)(As + row * 128 + (byo ^ ((row & 7) << 4)));
            }
#pragma unroll
            for (int ni = 0; ni < 4; ++ni) {
                const int row = wn + ni * 16 + lc;
                bfr[ni] = *(const bf16x8*)(Bs + row * 128 + (byo ^ ((row & 7) << 4)));
            }
#pragma unroll
            for (int mi = 0; mi < 4; ++mi)
#pragma unroll
                for (int ni = 0; ni < 4; ++ni)
                    acc[mi][ni] = mfma16(af[mi], bfr[ni], acc[mi][ni]);
        }
        __syncthreads();
    }
}

// ---------------------------------------------------------------- fused QKV projection
// r14: 256x128 tile, 768 blocks = EXACTLY 3/CU (r12's 384 blocks at 1/CU left
// 25% of CUs idle in round 2 -- makespan defect). Schedule = r12's verified
// phase shape (16 MFMA + 2 barriers per phase), 2 phases/K-tile:
//   P_A: read af-M0(8) + bfr(4); stage A0(u+1)->nb; barrier; MFMA16; barrier.
//   P_B: read af-M1(8); stage A1(u+1)->nb + B(u+2)->cb (cb B-region dead
//        after P_A reads -- r12's verified in-place trick); barrier; MFMA16;
//        vmcnt(2) [keeps newest B(u+2) pair, drains A(u+1); B(u+1) older ->
//        drained]; barrier.
// LDS 96KB = 2buf x (A 32K + B 16K). waves_per_eu(2,2).
__global__ __launch_bounds__(512) __attribute__((amdgpu_waves_per_eu(2, 2)))
void qkv_gemm(const u16* __restrict__ xb, const u16* __restrict__ wqkv,
              const float* __restrict__ bq, const float* __restrict__ bk,
              const float* __restrict__ bv,
              u16* __restrict__ qo, u16* __restrict__ ko, u16* __restrict__ vt) {
    __shared__ char lds[98304];
    const int tid = threadIdx.x;
    const int w = tid >> 6, l = tid & 63;
    const int lg = l >> 4, lc = l & 15;
    const int wr = w >> 2, wc = w & 3;           // wave grid 2(M) x 4(N of 32)
    const int id = blockIdx.x;
    const int xcd = id & 7, sl = id >> 3;        // 96 slots/XCD
    const int nIdx = sl >> 2, mloc = sl & 3;     // 24 N-tiles x 4 M-tiles
    const int m0 = (xcd * 4 + mloc) * 256;
    const int n0 = nIdx * 128;

    f32x4 acc[8][2] = {};                        // wave output 128x32

#define STAGE_A(H, KT, BUFP)                                                                     \
    {                                                                                            \
        _Pragma("unroll")                                                                        \
        for (int i_ = 0; i_ < 2; ++i_) {                                                         \
            const int e_ = i_ * 512 + tid;                                                       \
            const int row_ = e_ >> 3, c_ = e_ & 7;                                               \
            const int cs_ = c_ ^ (row_ & 7);                                                     \
            load_lds16(xb + (size_t)(m0 + (H) * 128 + row_) * 1024 + (KT) + cs_ * 8,             \
                       (BUFP) + (H) * 16384 + i_ * 8192 + w * 1024);                             \
        }                                                                                        \
    }
#define STAGE_B(KT, BUFP)                                                                        \
    {                                                                                            \
        _Pragma("unroll")                                                                        \
        for (int i_ = 0; i_ < 2; ++i_) {                                                         \
            const int e_ = i_ * 512 + tid;                                                       \
            const int row_ = e_ >> 3, c_ = e_ & 7;                                               \
            const int cs_ = c_ ^ (row_ & 7);                                                     \
            load_lds16(wqkv + (size_t)(n0 + row_) * 1024 + (KT) + cs_ * 8,                       \
                       (BUFP) + 32768 + i_ * 8192 + w * 1024);                                   \
        }                                                                                        \
    }
#define PHASE_BARRIER()                                                                          \
    {                                                                                            \
        __builtin_amdgcn_sched_barrier(0);                                                       \
        __builtin_amdgcn_s_barrier();                                                            \
    }

    // ---- prologue: A(0),B(0) -> buf0; B(1) -> buf1
    STAGE_A(0, 0, lds) STAGE_A(1, 0, lds)
    STAGE_B(0, lds)
    STAGE_B(64, lds + 49152)
    asm volatile("s_waitcnt vmcnt(0)" ::: "memory");
    PHASE_BARRIER()

    for (int u = 0; u < 16; ++u) {
        const int kt = u * 64;
        char* cb = lds + (u & 1) * 49152;
        char* nb = lds + ((u + 1) & 1) * 49152;
        char* abase = cb + wr * 16384;
        char* bbase = cb + 32768;
        bf16x8 af[4][2], bfr[2][2];
        // ---------- P_A: quadrant M0
#pragma unroll
        for (int m = 0; m < 4; ++m) {
            const int row = m * 16 + lc;
#pragma unroll
            for (int kk = 0; kk < 2; ++kk)
                af[m][kk] = *(const bf16x8*)(abase + row * 128 + ((kk * 64 + lg * 16) ^ ((row & 7) << 4)));
        }
#pragma unroll
        for (int n = 0; n < 2; ++n) {
            const int row = wc * 32 + n * 16 + lc;
#pragma unroll
            for (int kk = 0; kk < 2; ++kk)
                bfr[n][kk] = *(const bf16x8*)(bbase + row * 128 + ((kk * 64 + lg * 16) ^ ((row & 7) << 4)));
        }
        if (u < 15) STAGE_A(0, kt + 64, nb)
        PHASE_BARRIER()
        __builtin_amdgcn_s_setprio(1);
#pragma unroll
        for (int m = 0; m < 4; ++m)
#pragma unroll
            for (int n = 0; n < 2; ++n)
#pragma unroll
                for (int kk = 0; kk < 2; ++kk)
                    acc[m][n] = mfma16(af[m][kk], bfr[n][kk], acc[m][n]);
        __builtin_amdgcn_s_setprio(0);
        PHASE_BARRIER()
        // ---------- P_B: quadrant M1; B LDS of cb dead -> stage B(u+2) in place
#pragma unroll
        for (int m = 0; m < 4; ++m) {
            const int row = 64 + m * 16 + lc;
#pragma unroll
            for (int kk = 0; kk < 2; ++kk)
                af[m][kk] = *(const bf16x8*)(abase + row * 128 + ((kk * 64 + lg * 16) ^ ((row & 7) << 4)));
        }
        if (u < 15) STAGE_A(1, kt + 64, nb)
        if (u < 14) STAGE_B(kt + 128, cb)
        PHASE_BARRIER()
        __builtin_amdgcn_s_setprio(1);
#pragma unroll
        for (int m = 0; m < 4; ++m)
#pragma unroll
            for (int n = 0; n < 2; ++n)
#pragma unroll
                for (int kk = 0; kk < 2; ++kk)
                    acc[4 + m][n] = mfma16(af[m][kk], bfr[n][kk], acc[4 + m][n]);
        __builtin_amdgcn_s_setprio(0);
        if (u >= 14) { asm volatile("s_waitcnt vmcnt(0)" ::: "memory"); }
        else         { asm volatile("s_waitcnt vmcnt(2)" ::: "memory"); }
        PHASE_BARRIER()
    }

    // ---- epilogue: bias (+ CLOG fold for Q), scatter to (B,H,T,D)/(B,H,D,T)
    const int nw0 = n0 + wc * 32;
    const int whichw = nw0 >> 10;                // wave-uniform (32-aligned span)
    const float* bias = whichw == 0 ? bq : (whichw == 1 ? bk : bv);
    if (whichw == 2) {
#pragma unroll
        for (int mi = 0; mi < 8; ++mi)
#pragma unroll
            for (int ni = 0; ni < 2; ++ni) {
                const int ng = nw0 + ni * 16 + lc;
                const int c = ng & 1023;
                const int h = c >> 6, d = c & 63;
                const float bb = bias[c];
                const int t0 = m0 + wr * 128 + mi * 16 + lg * 4;
                const int b = t0 >> 11, t = t0 & 2047;
                uint32_t w0 = (uint32_t)f2bf(acc[mi][ni][0] + bb) | ((uint32_t)f2bf(acc[mi][ni][1] + bb) << 16);
                uint32_t w1 = (uint32_t)f2bf(acc[mi][ni][2] + bb) | ((uint32_t)f2bf(acc[mi][ni][3] + bb) << 16);
                uint2 pk; pk.x = w0; pk.y = w1;
                *(uint2*)(vt + (((size_t)(b * 16 + h)) * 64 + d) * 2048 + t) = pk;
            }
    } else {
        u16* outb = whichw == 0 ? qo : ko;
        const float sc = whichw == 0 ? CLOG : 1.0f;
#pragma unroll
        for (int mi = 0; mi < 8; ++mi)
#pragma unroll
            for (int ni = 0; ni < 2; ++ni)
#pragma unroll
                for (int r = 0; r < 4; ++r) {
                    const int m = m0 + wr * 128 + mi * 16 + lg * 4 + r;
                    const int ng = nw0 + ni * 16 + lc;
                    const int c = ng & 1023;
                    const float v = (acc[mi][ni][r] + bias[c]) * sc;
                    const int h = c >> 6, d = c & 63;
                    const int b = m >> 11, t = m & 2047;
                    outb[(((size_t)(b * 16 + h)) * 2048 + t) * 64 + d] = f2bf(v);
                }
    }
}

// ---------------------------------------------------------------- flash attention (causal)
// r12 version EXACTLY (best measured: 80.2us). Paired-strip 8-wave blocks,
// max-free softmax, Q pre-scaled by CLOG. r13 wave-widening REVERTED (halved
// LDS conflicts but halved occupancy -> latency-bound regression; attn needs
// 16 waves/CU TLP).
__global__ __launch_bounds__(512) __attribute__((amdgpu_waves_per_eu(4, 4)))
void attn_kernel(const u16* __restrict__ qbuf, const u16* __restrict__ kbuf,
                 const u16* __restrict__ vtb, u16* __restrict__ attb) {
    __shared__ char lds[32768];  // [parity][ K 8KB | Vt 8KB ]
    const int tid = threadIdx.x;
    const int w = tid >> 6, l = tid & 63;        // w 0..7
    const int l31 = l & 31, hi = l >> 5;
    const int id = blockIdx.x;
    const int xcd = id & 7, slot = id >> 3;      // slot 0..63 per XCD
    const int round = slot >> 5, k5 = slot & 31;
    const int p = round ? (7 - (k5 & 7)) : (k5 & 7);   // CU pair (p,7-p): rounds sum 50
    const int bh = xcd * 8 + round * 4 + (k5 >> 3);    // 8 heads/XCD (4 per round)
    const int ws = p + (w >> 2) * 8;             // wave's strip: sA=p or sB=p+8
    const size_t base = (size_t)bh * 2048 * 64;  // same stride for (B,H,T,D)/(B,H,D,T)
    const int qw0 = ws * 128 + (w & 3) * 32;     // this wave's 32 q rows
    const int jmax = (qw0 + 31) >> 6;            // last KV tile this wave needs
    const int tH = 2 * p + 18;                   // tiles staged (covers sB=p+8)
    const int qg = qw0 + l31;

    bf16x8 aqf[4];
#pragma unroll
    for (int t = 0; t < 4; ++t)
        aqf[t] = *(const bf16x8*)(qbuf + base + (size_t)(qw0 + l31) * 64 + t * 16 + hi * 8);

    f32x16 oacc[2];
#pragma unroll
    for (int i = 0; i < 16; ++i) { oacc[0][i] = 0.f; oacc[1][i] = 0.f; }
    float lrun = 0.f;   // OWN-HALF unnormalized sums (cross-half add deferred)

#define ISSUE_K(J, BUF)                                                                          \
    {                                                                                            \
        const int row = tid >> 3, c = tid & 7;                                                   \
        const int cs = c ^ (row & 7);                                                            \
        load_lds16(kbuf + base + (size_t)((J) * 64 + row) * 64 + cs * 8, (BUF) + w * 1024);      \
    }
#define ISSUE_VT(J, BUF)                                                                         \
    {                                                                                            \
        const int row = tid >> 3, c = tid & 7;                                                   \
        const int cs = c ^ (row & 7);                                                            \
        load_lds16(vtb + base + (size_t)row * 2048 + (J) * 64 + cs * 8, (BUF) + w * 1024);       \
    }

#define PVSTEP(W, KL, KS)                                                       \
    {                                                                           \
        const uint32_t wa = W[4 * (KL) + 0], wb_ = W[4 * (KL) + 1];             \
        const uint32_t wc = W[4 * (KL) + 2], wd = W[4 * (KL) + 3];              \
        const uint32_t xa = (uint32_t)__shfl_xor((int)wa, 32, 64);              \
        const uint32_t xb = (uint32_t)__shfl_xor((int)wb_, 32, 64);             \
        const uint32_t xc = (uint32_t)__shfl_xor((int)wc, 32, 64);              \
        const uint32_t xd = (uint32_t)__shfl_xor((int)wd, 32, 64);              \
        u32x4 pw;                                                               \
        pw[0] = hi ? xc : wa;                                                   \
        pw[1] = hi ? xd : wb_;                                                  \
        pw[2] = hi ? wc : xa;                                                   \
        pw[3] = hi ? wd : xb;                                                   \
        const bf16x8 paf = __builtin_bit_cast(bf16x8, pw);                      \
        __builtin_amdgcn_s_setprio(1);                                          \
        _Pragma("unroll")                                                       \
        for (int nb = 0; nb < 2; ++nb) {                                        \
            const int vrow = nb * 32 + l31;                                     \
            const bf16x8 bvf = *(const bf16x8*)(Vt + vrow * 128 +               \
                (((KS) * 32 + hi * 16) ^ ((vrow & 7) << 4)));                   \
            oacc[nb] = mfma32(paf, bvf, oacc[nb]);                              \
        }                                                                       \
        __builtin_amdgcn_s_setprio(0);                                          \
    }

// max-free, pre-scaled: P = exp2(S); own-half pairwise sum; pack to bf16 pairs
#define SOFTMAX_PACK(SF, WV)                                                    \
    {                                                                           \
        float ps[8];                                                            \
        _Pragma("unroll")                                                       \
        for (int i = 0; i < 8; ++i) {                                           \
            const float p0 = exp2f((SF)[2 * i]);                                \
            const float p1 = exp2f((SF)[2 * i + 1]);                            \
            (SF)[2 * i] = p0;                                                   \
            (SF)[2 * i + 1] = p1;                                               \
            ps[i] = p0 + p1;                                                    \
        }                                                                       \
        lrun += ((ps[0] + ps[1]) + (ps[2] + ps[3])) +                           \
                ((ps[4] + ps[5]) + (ps[6] + ps[7]));                            \
        _Pragma("unroll")                                                       \
        for (int i = 0; i < 8; ++i) {                                           \
            uint32_t ww;                                                        \
            asm("v_cvt_pk_bf16_f32 %0, %1, %2"                                  \
                : "=v"(ww) : "v"((SF)[2 * i]), "v"((SF)[2 * i + 1]));           \
            (WV)[i] = ww;                                                       \
        }                                                                       \
    }

    ISSUE_K(0, lds);
    ISSUE_VT(0, lds + 8192);
    for (int j = 0; j < tH; ++j) {
        __syncthreads();
        if (j + 1 < tH) {
            char* nb2 = lds + ((j + 1) & 1) * 16384;
            ISSUE_K(j + 1, nb2);
            ISSUE_VT(j + 1, nb2 + 8192);
        }
        if (j <= jmax) {
            char* Ks = lds + (j & 1) * 16384;
            char* Vt = Ks + 8192;
            const bool two = (qw0 >= j * 64 + 32);   // wave-uniform
            f32x16 sf0, sf1;
#pragma unroll
            for (int i = 0; i < 16; ++i) sf0[i] = 0.f;
            __builtin_amdgcn_s_setprio(1);
#pragma unroll
            for (int t = 0; t < 4; ++t) {
                const bf16x8 ak = *(const bf16x8*)(Ks + l31 * 128 + ((t * 32 + hi * 16) ^ ((l31 & 7) << 4)));
                sf0 = mfma32(ak, aqf[t], sf0);
            }
            __builtin_amdgcn_s_setprio(0);
            if (two) {
#pragma unroll
                for (int i = 0; i < 16; ++i) sf1[i] = 0.f;
                __builtin_amdgcn_s_setprio(1);
#pragma unroll
                for (int t = 0; t < 4; ++t) {
                    const int row = 32 + l31;
                    const bf16x8 ak = *(const bf16x8*)(Ks + row * 128 + ((t * 32 + hi * 16) ^ ((row & 7) << 4)));
                    sf1 = mfma32(ak, aqf[t], sf1);
                }
                __builtin_amdgcn_s_setprio(0);
                if (qw0 == j * 64 + 32) {
#pragma unroll
                    for (int rg = 0; rg < 16; ++rg) {
                        const int ss = j * 64 + 32 + (rg & 3) + 8 * (rg >> 2) + 4 * hi;
                        if (ss > qg) sf1[rg] = -3.0e38f;
                    }
                }
            } else {
#pragma unroll
                for (int rg = 0; rg < 16; ++rg) {
                    const int ss = j * 64 + (rg & 3) + 8 * (rg >> 2) + 4 * hi;
                    if (ss > qg) sf0[rg] = -3.0e38f;
                }
            }
            uint32_t wv[8];
            SOFTMAX_PACK(sf0, wv)
            PVSTEP(wv, 0, 0)
            PVSTEP(wv, 1, 1)
            if (two) {
                SOFTMAX_PACK(sf1, wv)
                PVSTEP(wv, 0, 2)
                PVSTEP(wv, 1, 3)
            }
        }
    }
    // ---- epilogue: cross-half lrun, normalize (v_rcp), write (B,T,C) bf16
    const int b = bh >> 4, h = bh & 15;
    const float lfull = lrun + __shfl_xor(lrun, 32, 64);
    const float inv = rcpf(lfull);
#pragma unroll
    for (int rq = 0; rq < 4; ++rq)
#pragma unroll
        for (int rr = 0; rr < 4; ++rr) {
            const int q = rr + 8 * rq + 4 * hi;
            const float iv = __shfl(inv, q | (l & 32), 64);
            const int t = qw0 + q;
#pragma unroll
            for (int nb = 0; nb < 2; ++nb) {
                const int c = h * 64 + nb * 32 + l31;
                attb[((size_t)(b * 2048 + t)) * 1024 + c] = f2bf(oacc[nb][rq * 4 + rr] * iv);
            }
        }
}

// ---------------------------------------------------------------- output projection (fp32 out)
__global__ __launch_bounds__(256) void proj_gemm(const u16* __restrict__ attb, const u16* __restrict__ wpb,
                                                 const float* __restrict__ bp, float* __restrict__ out) {
    __shared__ char lds[32768];
    f32x4 acc[4][4] = {};
    const int id = blockIdx.x;
    const int xcd = id & 7, sl = id >> 3;
    const int nIdx = sl >> 3, mloc = sl & 7;
    const int m0 = (xcd * 8 + mloc) * 128;
    const int n0 = nIdx * 128;
    gemm_core<1024>(attb, wpb, m0, n0, lds, acc);
    const int tid = threadIdx.x;
    const int w = tid >> 6, l = tid & 63;
    const int lg = l >> 4, lc = l & 15;
    const int wm = (w >> 1) * 64, wn = (w & 1) * 64;
#pragma unroll
    for (int mi = 0; mi < 4; ++mi)
#pragma unroll
        for (int ni = 0; ni < 4; ++ni)
#pragma unroll
            for (int r = 0; r < 4; ++r) {
                const int m = m0 + wm + mi * 16 + lg * 4 + r;
                const int n = n0 + wn + ni * 16 + lc;
                out[(size_t)m * 1024 + n] = acc[mi][ni][r] + bp[n];
            }
}

// ---------------------------------------------------------------- launch
extern "C" void kernel_launch(void* const* d_in, const int* in_sizes, int n_in,
                              void* d_out, int out_size, void* d_ws, size_t ws_size,
                              hipStream_t stream) {
    const float* x  = (const float*)d_in[0];
    const float* Wk = (const float*)d_in[1];
    const float* bk = (const float*)d_in[2];
    const float* Wq = (const float*)d_in[3];
    const float* bq = (const float*)d_in[4];
    const float* Wv = (const float*)d_in[5];
    const float* bv = (const float*)d_in[6];
    const float* Wp = (const float*)d_in[7];
    const float* bp = (const float*)d_in[8];
    char* ws = (char*)d_ws;
    u16* xb   = (u16*)(ws);
    u16* wqkv = (u16*)(ws + 16777216);
    u16* wpb  = (u16*)(ws + 23068672);
    u16* qbuf = (u16*)(ws + 25165824);
    u16* kbuf = (u16*)(ws + 41943040);
    u16* vtb  = (u16*)(ws + 58720256);   // (B,H,D,T) pre-transposed V
    u16* attb = (u16*)(ws + 75497472);

    cast_all<<<12288, 256, 0, stream>>>(x, Wq, Wk, Wv, Wp, xb, wqkv, wpb);
    qkv_gemm<<<768, 512, 0, stream>>>(xb, wqkv, bq, bk, bv, qbuf, kbuf, vtb);
    attn_kernel<<<512, 512, 0, stream>>>(qbuf, kbuf, vtb, attb);
    proj_gemm<<<512, 256, 0, stream>>>(attb, wpb, bp, (float*)d_out);
}

// Round 16
// 163.582 us; speedup vs baseline: 1.1556x; 1.0578x over previous
//
#include <hip/hip_runtime.h>
#include <stdint.h>

typedef unsigned short u16;
typedef __attribute__((ext_vector_type(8))) __bf16 bf16x8;
typedef __attribute__((ext_vector_type(8))) short short8;
typedef __attribute__((ext_vector_type(4))) float f32x4;
typedef __attribute__((ext_vector_type(16))) float f32x16;
typedef __attribute__((ext_vector_type(4))) uint32_t u32x4;

#define AS1 __attribute__((address_space(1)))
#define AS3 __attribute__((address_space(3)))

__device__ __forceinline__ void load_lds16(const void* g, void* l) {
    __builtin_amdgcn_global_load_lds((AS1 void*)g, (AS3 void*)l, 16, 0, 0);
}

__device__ __forceinline__ u16 f2bf(float f) {
    uint32_t u = __builtin_bit_cast(uint32_t, f);
    u += 0x7FFFu + ((u >> 16) & 1u);
    return (u16)(u >> 16);
}

__device__ __forceinline__ f32x4 mfma16(bf16x8 a, bf16x8 b, f32x4 c) {
    return __builtin_amdgcn_mfma_f32_16x16x32_bf16(a, b, c, 0, 0, 0);
}
__device__ __forceinline__ f32x16 mfma32(bf16x8 a, bf16x8 b, f32x16 c) {
    return __builtin_amdgcn_mfma_f32_32x32x16_bf16(a, b, c, 0, 0, 0);
}

__device__ __forceinline__ float rcpf(float x) {
    float r;
    asm("v_rcp_f32 %0, %1" : "=v"(r) : "v"(x));
    return r;
}

#define CLOG 0.18033688f   /* 0.125 * log2(e) -- folded into Q at qkv epilogue */

// ---------------------------------------------------------------- fused cast f32->bf16
__global__ __launch_bounds__(256) void cast_all(const float* __restrict__ x,
                                                const float* __restrict__ wq,
                                                const float* __restrict__ wk,
                                                const float* __restrict__ wv,
                                                const float* __restrict__ wp,
                                                u16* __restrict__ xb,
                                                u16* __restrict__ wqkv,
                                                u16* __restrict__ wpb) {
    const int bid = blockIdx.x;
    const float* src;
    u16* dst;
    int boff;
    if (bid < 8192)       { src = x;  dst = xb;             boff = bid; }
    else if (bid < 9216)  { src = wq; dst = wqkv;           boff = bid - 8192; }
    else if (bid < 10240) { src = wk; dst = wqkv + 1048576; boff = bid - 9216; }
    else if (bid < 11264) { src = wv; dst = wqkv + 2097152; boff = bid - 10240; }
    else                  { src = wp; dst = wpb;            boff = bid - 11264; }
    const int i = (boff * 256 + threadIdx.x) * 4;
    const float4 v = *(const float4*)(src + i);
    u16 o0 = f2bf(v.x), o1 = f2bf(v.y), o2 = f2bf(v.z), o3 = f2bf(v.w);
    uint32_t lo = (uint32_t)o0 | ((uint32_t)o1 << 16);
    uint32_t hi = (uint32_t)o2 | ((uint32_t)o3 << 16);
    uint2 p; p.x = lo; p.y = hi;
    *(uint2*)(dst + i) = p;
}

// ---------------------------------------------------------------- 128x128 GEMM core (proj)
template<int KDIM>
__device__ __forceinline__ void gemm_core(const u16* __restrict__ A, const u16* __restrict__ Bw,
                                          int m0, int n0, char* lds, f32x4 acc[4][4]) {
    const int tid = threadIdx.x;
    const int w = tid >> 6, l = tid & 63;
    const int lg = l >> 4, lc = l & 15;
    const int wm = (w >> 1) * 64, wn = (w & 1) * 64;
    char* As = lds;
    char* Bs = lds + 16384;
    for (int kt = 0; kt < KDIM; kt += 64) {
#pragma unroll
        for (int i = 0; i < 4; ++i) {
            const int e = i * 256 + tid;
            const int row = e >> 3, c = e & 7;
            const int cs = c ^ (row & 7);
            load_lds16(A + (size_t)(m0 + row) * KDIM + kt + cs * 8, As + i * 4096 + w * 1024);
            load_lds16(Bw + (size_t)(n0 + row) * KDIM + kt + cs * 8, Bs + i * 4096 + w * 1024);
        }
        __syncthreads();
#pragma unroll
        for (int kk = 0; kk < 2; ++kk) {
            bf16x8 af[4], bfr[4];
            const int byo = kk * 64 + lg * 16;
#pragma unroll
            for (int mi = 0; mi < 4; ++mi) {
                const int row = wm + mi * 16 + lc;
                af[mi] = *(const bf16x8*)(As + row * 128 + (byo ^ ((row & 7) << 4)));
            }
#pragma unroll
            for (int ni = 0; ni < 4; ++ni) {
                const int row = wn + ni * 16 + lc;
                bfr[ni] = *(const bf16x8*)(Bs + row * 128 + (byo ^ ((row & 7) << 4)));
            }
#pragma unroll
            for (int mi = 0; mi < 4; ++mi)
#pragma unroll
                for (int ni = 0; ni < 4; ++ni)
                    acc[mi][ni] = mfma16(af[mi], bfr[ni], acc[mi][ni]);
        }
        __syncthreads();
    }
}

// ---------------------------------------------------------------- fused QKV projection
// r16: r15 split-grid with the ONE-LINE FIX: NIA = BM/128 (was BM/256 -- A-half
// staging needs (BM/2 rows x 128B)/(512thr x 16B) = BM/128 issues; the wrong
// constant left A rows unstaged in BOTH instantiations -> r15's NaN).
//   launch 1: BM=256, 256 blocks = tiles nIdx 0..7  (Q+K), 1/CU exact.
//   launch 2: BM=128, 256 blocks = tiles nIdx 8..11 (V) split in M, 1/CU.
// vmcnt invariants re-verified for both BM (prologue keeps B(1) quad; steady
// gate drains A(u+1), keeps newest B(u+2) quad).
template<int BM>
__global__ __launch_bounds__(512) __attribute__((amdgpu_waves_per_eu(2, 2)))
void qkv_gemm(const u16* __restrict__ xb, const u16* __restrict__ wqkv,
              const float* __restrict__ bq, const float* __restrict__ bk,
              const float* __restrict__ bv,
              u16* __restrict__ qo, u16* __restrict__ ko, u16* __restrict__ vt) {
    constexpr int ABUF = BM * 128;           // A bytes per buffer ([BM][128B])
    constexpr int BUFS = ABUF + 32768;       // buffer stride (B region fixed 32KB)
    constexpr int MF = BM / 32;              // acc m-frags per wave (8 / 4)
    constexpr int MH = MF / 2;               // frags per M-half (4 / 2)
    constexpr int NIA = BM / 128;            // A stage issues per half (2 / 1)  [r15 FIX]
    __shared__ char lds[2 * BUFS];
    const int tid = threadIdx.x;
    const int w = tid >> 6, l = tid & 63;
    const int lg = l >> 4, lc = l & 15;
    const int wr = w >> 2, wc = w & 3;       // wave grid 2(M) x 4(N)
    const int id = blockIdx.x;
    const int xcd = id & 7, sl = id >> 3;    // 32 slots/XCD
    int m0, n0;
    if constexpr (BM == 256) {
        const int nIdx = sl >> 2, mloc = sl & 3;     // nIdx 0..7
        m0 = (xcd * 4 + mloc) * 256;
        n0 = nIdx * 256;
    } else {
        const int osl = 32 + (sl >> 1), mh = sl & 1; // original sl 32..47
        const int nIdx = osl >> 2, mloc = osl & 3;   // nIdx 8..11
        m0 = (xcd * 4 + mloc) * 256 + mh * 128;
        n0 = nIdx * 256;
    }

    f32x4 acc[MF][4] = {};                   // wave output (BM/2) x 64

    auto stage_a = [&](int H, int KT, char* BUFP) {
#pragma unroll
        for (int i_ = 0; i_ < NIA; ++i_) {
            const int e_ = i_ * 512 + tid;
            const int row_ = e_ >> 3, c_ = e_ & 7;
            const int cs_ = c_ ^ (row_ & 7);
            load_lds16(xb + (size_t)(m0 + H * (BM / 2) + row_) * 1024 + KT + cs_ * 8,
                       BUFP + H * (ABUF / 2) + i_ * 8192 + w * 1024);
        }
    };
    auto stage_b = [&](int H, int KT, char* BUFP) {
#pragma unroll
        for (int i_ = 0; i_ < 2; ++i_) {
            const int e_ = i_ * 512 + tid;
            const int row_ = e_ >> 3, c_ = e_ & 7;
            const int cs_ = c_ ^ (row_ & 7);
            load_lds16(wqkv + (size_t)(n0 + H * 128 + row_) * 1024 + KT + cs_ * 8,
                       BUFP + ABUF + H * 16384 + i_ * 8192 + w * 1024);
        }
    };
#define PHASE_BARRIER()                                                                          \
    {                                                                                            \
        __builtin_amdgcn_sched_barrier(0);                                                       \
        __builtin_amdgcn_s_barrier();                                                            \
    }

    // ---- prologue: tile0 fully + B halves of tile1
    stage_a(0, 0, lds); stage_a(1, 0, lds);
    stage_b(0, 0, lds); stage_b(1, 0, lds);
    stage_b(0, 64, lds + BUFS); stage_b(1, 64, lds + BUFS);
    asm volatile("s_waitcnt vmcnt(4)" ::: "memory");
    PHASE_BARRIER()

    for (int u = 0; u < 16; ++u) {
        const int kt = u * 64;
        char* cb = lds + (u & 1) * BUFS;
        char* nb = lds + ((u + 1) & 1) * BUFS;
        char* abase = cb + wr * (ABUF / 2);
        char* bbase = cb + ABUF + (wc >> 1) * 16384;
        const int brl = (wc & 1) * 64;
        bf16x8 af[MH][2], bfr[4][2];
        // ---------- P0: quadrant (M0,N0)
#pragma unroll
        for (int m = 0; m < MH; ++m) {
            const int row = m * 16 + lc;
#pragma unroll
            for (int kk = 0; kk < 2; ++kk)
                af[m][kk] = *(const bf16x8*)(abase + row * 128 + ((kk * 64 + lg * 16) ^ ((row & 7) << 4)));
        }
#pragma unroll
        for (int n = 0; n < 2; ++n) {
            const int row = brl + n * 16 + lc;
#pragma unroll
            for (int kk = 0; kk < 2; ++kk)
                bfr[n][kk] = *(const bf16x8*)(bbase + row * 128 + ((kk * 64 + lg * 16) ^ ((row & 7) << 4)));
        }
        if (u < 15) stage_a(0, kt + 64, nb);
        PHASE_BARRIER()
        __builtin_amdgcn_s_setprio(1);
#pragma unroll
        for (int m = 0; m < MH; ++m)
#pragma unroll
            for (int n = 0; n < 2; ++n)
#pragma unroll
                for (int kk = 0; kk < 2; ++kk)
                    acc[m][n] = mfma16(af[m][kk], bfr[n][kk], acc[m][n]);
        __builtin_amdgcn_s_setprio(0);
        PHASE_BARRIER()
        // ---------- P1: quadrant (M0,N1)
#pragma unroll
        for (int n = 2; n < 4; ++n) {
            const int row = brl + n * 16 + lc;
#pragma unroll
            for (int kk = 0; kk < 2; ++kk)
                bfr[n][kk] = *(const bf16x8*)(bbase + row * 128 + ((kk * 64 + lg * 16) ^ ((row & 7) << 4)));
        }
        if (u < 15) stage_a(1, kt + 64, nb);
        PHASE_BARRIER()
        __builtin_amdgcn_s_setprio(1);
#pragma unroll
        for (int m = 0; m < MH; ++m)
#pragma unroll
            for (int n = 2; n < 4; ++n)
#pragma unroll
                for (int kk = 0; kk < 2; ++kk)
                    acc[m][n] = mfma16(af[m][kk], bfr[n][kk], acc[m][n]);
        __builtin_amdgcn_s_setprio(0);
        PHASE_BARRIER()
        // ---------- P2: quadrant (M1,N0) -- B LDS dead; stage B0(u+2) into cb
#pragma unroll
        for (int m = 0; m < MH; ++m) {
            const int row = (BM / 4) + m * 16 + lc;
#pragma unroll
            for (int kk = 0; kk < 2; ++kk)
                af[m][kk] = *(const bf16x8*)(abase + row * 128 + ((kk * 64 + lg * 16) ^ ((row & 7) << 4)));
        }
        if (u < 14) stage_b(0, kt + 128, cb);
        PHASE_BARRIER()
        __builtin_amdgcn_s_setprio(1);
#pragma unroll
        for (int m = 0; m < MH; ++m)
#pragma unroll
            for (int n = 0; n < 2; ++n)
#pragma unroll
                for (int kk = 0; kk < 2; ++kk)
                    acc[MH + m][n] = mfma16(af[m][kk], bfr[n][kk], acc[MH + m][n]);
        __builtin_amdgcn_s_setprio(0);
        PHASE_BARRIER()
        // ---------- P3: quadrant (M1,N1) -- no reads; stage B1(u+2); vmcnt gate
        if (u < 14) stage_b(1, kt + 128, cb);
        PHASE_BARRIER()
        __builtin_amdgcn_s_setprio(1);
#pragma unroll
        for (int m = 0; m < MH; ++m)
#pragma unroll
            for (int n = 2; n < 4; ++n)
#pragma unroll
                for (int kk = 0; kk < 2; ++kk)
                    acc[MH + m][n] = mfma16(af[m][kk], bfr[n][kk], acc[MH + m][n]);
        __builtin_amdgcn_s_setprio(0);
        if (u >= 14) { asm volatile("s_waitcnt vmcnt(0)" ::: "memory"); }
        else         { asm volatile("s_waitcnt vmcnt(4)" ::: "memory"); }
        PHASE_BARRIER()
    }

    // ---- epilogue: bias (+ CLOG fold for Q), scatter to (B,H,T,D)/(B,H,D,T)
    const int ngw = n0 + wc * 64;
    const int whichw = ngw >> 10;                // wave-uniform
    const float* bias = whichw == 0 ? bq : (whichw == 1 ? bk : bv);
    if (whichw == 2) {
#pragma unroll
        for (int mi = 0; mi < MF; ++mi)
#pragma unroll
            for (int ni = 0; ni < 4; ++ni) {
                const int ng = ngw + ni * 16 + lc;
                const int c = ng & 1023;
                const int h = c >> 6, d = c & 63;
                const float bb = bias[c];
                const int t0 = m0 + wr * (BM / 2) + mi * 16 + lg * 4;
                const int b = t0 >> 11, t = t0 & 2047;
                uint32_t w0 = (uint32_t)f2bf(acc[mi][ni][0] + bb) | ((uint32_t)f2bf(acc[mi][ni][1] + bb) << 16);
                uint32_t w1 = (uint32_t)f2bf(acc[mi][ni][2] + bb) | ((uint32_t)f2bf(acc[mi][ni][3] + bb) << 16);
                uint2 pk; pk.x = w0; pk.y = w1;
                *(uint2*)(vt + (((size_t)(b * 16 + h)) * 64 + d) * 2048 + t) = pk;
            }
    } else {
        u16* outb = whichw == 0 ? qo : ko;
        const float sc = whichw == 0 ? CLOG : 1.0f;
#pragma unroll
        for (int mi = 0; mi < MF; ++mi)
#pragma unroll
            for (int ni = 0; ni < 4; ++ni)
#pragma unroll
                for (int r = 0; r < 4; ++r) {
                    const int m = m0 + wr * (BM / 2) + mi * 16 + lg * 4 + r;
                    const int ng = ngw + ni * 16 + lc;
                    const int c = ng & 1023;
                    const float v = (acc[mi][ni][r] + bias[c]) * sc;
                    const int h = c >> 6, d = c & 63;
                    const int b = m >> 11, t = m & 2047;
                    outb[(((size_t)(b * 16 + h)) * 2048 + t) * 64 + d] = f2bf(v);
                }
    }
}

// ---------------------------------------------------------------- flash attention (causal)
// r12 version EXACTLY (best measured: 80.1us; counters reconfirmed r14).
__global__ __launch_bounds__(512) __attribute__((amdgpu_waves_per_eu(4, 4)))
void attn_kernel(const u16* __restrict__ qbuf, const u16* __restrict__ kbuf,
                 const u16* __restrict__ vtb, u16* __restrict__ attb) {
    __shared__ char lds[32768];  // [parity][ K 8KB | Vt 8KB ]
    const int tid = threadIdx.x;
    const int w = tid >> 6, l = tid & 63;        // w 0..7
    const int l31 = l & 31, hi = l >> 5;
    const int id = blockIdx.x;
    const int xcd = id & 7, slot = id >> 3;      // slot 0..63 per XCD
    const int round = slot >> 5, k5 = slot & 31;
    const int p = round ? (7 - (k5 & 7)) : (k5 & 7);   // CU pair (p,7-p): rounds sum 50
    const int bh = xcd * 8 + round * 4 + (k5 >> 3);    // 8 heads/XCD (4 per round)
    const int ws = p + (w >> 2) * 8;             // wave's strip: sA=p or sB=p+8
    const size_t base = (size_t)bh * 2048 * 64;  // same stride for (B,H,T,D)/(B,H,D,T)
    const int qw0 = ws * 128 + (w & 3) * 32;     // this wave's 32 q rows
    const int jmax = (qw0 + 31) >> 6;            // last KV tile this wave needs
    const int tH = 2 * p + 18;                   // tiles staged (covers sB=p+8)
    const int qg = qw0 + l31;

    bf16x8 aqf[4];
#pragma unroll
    for (int t = 0; t < 4; ++t)
        aqf[t] = *(const bf16x8*)(qbuf + base + (size_t)(qw0 + l31) * 64 + t * 16 + hi * 8);

    f32x16 oacc[2];
#pragma unroll
    for (int i = 0; i < 16; ++i) { oacc[0][i] = 0.f; oacc[1][i] = 0.f; }
    float lrun = 0.f;   // OWN-HALF unnormalized sums (cross-half add deferred)

#define ISSUE_K(J, BUF)                                                                          \
    {                                                                                            \
        const int row = tid >> 3, c = tid & 7;                                                   \
        const int cs = c ^ (row & 7);                                                            \
        load_lds16(kbuf + base + (size_t)((J) * 64 + row) * 64 + cs * 8, (BUF) + w * 1024);      \
    }
#define ISSUE_VT(J, BUF)                                                                         \
    {                                                                                            \
        const int row = tid >> 3, c = tid & 7;                                                   \
        const int cs = c ^ (row & 7);                                                            \
        load_lds16(vtb + base + (size_t)row * 2048 + (J) * 64 + cs * 8, (BUF) + w * 1024);       \
    }

#define PVSTEP(W, KL, KS)                                                       \
    {                                                                           \
        const uint32_t wa = W[4 * (KL) + 0], wb_ = W[4 * (KL) + 1];             \
        const uint32_t wc = W[4 * (KL) + 2], wd = W[4 * (KL) + 3];              \
        const uint32_t xa = (uint32_t)__shfl_xor((int)wa, 32, 64);              \
        const uint32_t xb = (uint32_t)__shfl_xor((int)wb_, 32, 64);             \
        const uint32_t xc = (uint32_t)__shfl_xor((int)wc, 32, 64);              \
        const uint32_t xd = (uint32_t)__shfl_xor((int)wd, 32, 64);              \
        u32x4 pw;                                                               \
        pw[0] = hi ? xc : wa;                                                   \
        pw[1] = hi ? xd : wb_;                                                  \
        pw[2] = hi ? wc : xa;                                                   \
        pw[3] = hi ? wd : xb;                                                   \
        const bf16x8 paf = __builtin_bit_cast(bf16x8, pw);                      \
        __builtin_amdgcn_s_setprio(1);                                          \
        _Pragma("unroll")                                                       \
        for (int nb = 0; nb < 2; ++nb) {                                        \
            const int vrow = nb * 32 + l31;                                     \
            const bf16x8 bvf = *(const bf16x8*)(Vt + vrow * 128 +               \
                (((KS) * 32 + hi * 16) ^ ((vrow & 7) << 4)));                   \
            oacc[nb] = mfma32(paf, bvf, oacc[nb]);                              \
        }                                                                       \
        __builtin_amdgcn_s_setprio(0);                                          \
    }

#define SOFTMAX_PACK(SF, WV)                                                    \
    {                                                                           \
        float ps[8];                                                            \
        _Pragma("unroll")                                                       \
        for (int i = 0; i < 8; ++i) {                                           \
            const float p0 = exp2f((SF)[2 * i]);                                \
            const float p1 = exp2f((SF)[2 * i + 1]);                            \
            (SF)[2 * i] = p0;                                                   \
            (SF)[2 * i + 1] = p1;                                               \
            ps[i] = p0 + p1;                                                    \
        }                                                                       \
        lrun += ((ps[0] + ps[1]) + (ps[2] + ps[3])) +                           \
                ((ps[4] + ps[5]) + (ps[6] + ps[7]));                            \
        _Pragma("unroll")                                                       \
        for (int i = 0; i < 8; ++i) {                                           \
            uint32_t ww;                                                        \
            asm("v_cvt_pk_bf16_f32 %0, %1, %2"                                  \
                : "=v"(ww) : "v"((SF)[2 * i]), "v"((SF)[2 * i + 1]));           \
            (WV)[i] = ww;                                                       \
        }                                                                       \
    }

    ISSUE_K(0, lds);
    ISSUE_VT(0, lds + 8192);
    for (int j = 0; j < tH; ++j) {
        __syncthreads();
        if (j + 1 < tH) {
            char* nb2 = lds + ((j + 1) & 1) * 16384;
            ISSUE_K(j + 1, nb2);
            ISSUE_VT(j + 1, nb2 + 8192);
        }
        if (j <= jmax) {
            char* Ks = lds + (j & 1) * 16384;
            char* Vt = Ks + 8192;
            const bool two = (qw0 >= j * 64 + 32);   // wave-uniform
            f32x16 sf0, sf1;
#pragma unroll
            for (int i = 0; i < 16; ++i) sf0[i] = 0.f;
            __builtin_amdgcn_s_setprio(1);
#pragma unroll
            for (int t = 0; t < 4; ++t) {
                const bf16x8 ak = *(const bf16x8*)(Ks + l31 * 128 + ((t * 32 + hi * 16) ^ ((l31 & 7) << 4)));
                sf0 = mfma32(ak, aqf[t], sf0);
            }
            __builtin_amdgcn_s_setprio(0);
            if (two) {
#pragma unroll
                for (int i = 0; i < 16; ++i) sf1[i] = 0.f;
                __builtin_amdgcn_s_setprio(1);
#pragma unroll
                for (int t = 0; t < 4; ++t) {
                    const int row = 32 + l31;
                    const bf16x8 ak = *(const bf16x8*)(Ks + row * 128 + ((t * 32 + hi * 16) ^ ((row & 7) << 4)));
                    sf1 = mfma32(ak, aqf[t], sf1);
                }
                __builtin_amdgcn_s_setprio(0);
                if (qw0 == j * 64 + 32) {
#pragma unroll
                    for (int rg = 0; rg < 16; ++rg) {
                        const int ss = j * 64 + 32 + (rg & 3) + 8 * (rg >> 2) + 4 * hi;
                        if (ss > qg) sf1[rg] = -3.0e38f;
                    }
                }
            } else {
#pragma unroll
                for (int rg = 0; rg < 16; ++rg) {
                    const int ss = j * 64 + (rg & 3) + 8 * (rg >> 2) + 4 * hi;
                    if (ss > qg) sf0[rg] = -3.0e38f;
                }
            }
            uint32_t wv[8];
            SOFTMAX_PACK(sf0, wv)
            PVSTEP(wv, 0, 0)
            PVSTEP(wv, 1, 1)
            if (two) {
                SOFTMAX_PACK(sf1, wv)
                PVSTEP(wv, 0, 2)
                PVSTEP(wv, 1, 3)
            }
        }
    }
    // ---- epilogue: cross-half lrun, normalize (v_rcp), write (B,T,C) bf16
    const int b = bh >> 4, h = bh & 15;
    const float lfull = lrun + __shfl_xor(lrun, 32, 64);
    const float inv = rcpf(lfull);
#pragma unroll
    for (int rq = 0; rq < 4; ++rq)
#pragma unroll
        for (int rr = 0; rr < 4; ++rr) {
            const int q = rr + 8 * rq + 4 * hi;
            const float iv = __shfl(inv, q | (l & 32), 64);
            const int t = qw0 + q;
#pragma unroll
            for (int nb = 0; nb < 2; ++nb) {
                const int c = h * 64 + nb * 32 + l31;
                attb[((size_t)(b * 2048 + t)) * 1024 + c] = f2bf(oacc[nb][rq * 4 + rr] * iv);
            }
        }
}

// ---------------------------------------------------------------- output projection (fp32 out)
__global__ __launch_bounds__(256) void proj_gemm(const u16* __restrict__ attb, const u16* __restrict__ wpb,
                                                 const float* __restrict__ bp, float* __restrict__ out) {
    __shared__ char lds[32768];
    f32x4 acc[4][4] = {};
    const int id = blockIdx.x;
    const int xcd = id & 7, sl = id >> 3;
    const int nIdx = sl >> 3, mloc = sl & 7;
    const int m0 = (xcd * 8 + mloc) * 128;
    const int n0 = nIdx * 128;
    gemm_core<1024>(attb, wpb, m0, n0, lds, acc);
    const int tid = threadIdx.x;
    const int w = tid >> 6, l = tid & 63;
    const int lg = l >> 4, lc = l & 15;
    const int wm = (w >> 1) * 64, wn = (w & 1) * 64;
#pragma unroll
    for (int mi = 0; mi < 4; ++mi)
#pragma unroll
        for (int ni = 0; ni < 4; ++ni)
#pragma unroll
            for (int r = 0; r < 4; ++r) {
                const int m = m0 + wm + mi * 16 + lg * 4 + r;
                const int n = n0 + wn + ni * 16 + lc;
                out[(size_t)m * 1024 + n] = acc[mi][ni][r] + bp[n];
            }
}

// ---------------------------------------------------------------- launch
extern "C" void kernel_launch(void* const* d_in, const int* in_sizes, int n_in,
                              void* d_out, int out_size, void* d_ws, size_t ws_size,
                              hipStream_t stream) {
    const float* x  = (const float*)d_in[0];
    const float* Wk = (const float*)d_in[1];
    const float* bk = (const float*)d_in[2];
    const float* Wq = (const float*)d_in[3];
    const float* bq = (const float*)d_in[4];
    const float* Wv = (const float*)d_in[5];
    const float* bv = (const float*)d_in[6];
    const float* Wp = (const float*)d_in[7];
    const float* bp = (const float*)d_in[8];
    char* ws = (char*)d_ws;
    u16* xb   = (u16*)(ws);
    u16* wqkv = (u16*)(ws + 16777216);
    u16* wpb  = (u16*)(ws + 23068672);
    u16* qbuf = (u16*)(ws + 25165824);
    u16* kbuf = (u16*)(ws + 41943040);
    u16* vtb  = (u16*)(ws + 58720256);   // (B,H,D,T) pre-transposed V
    u16* attb = (u16*)(ws + 75497472);

    cast_all<<<12288, 256, 0, stream>>>(x, Wq, Wk, Wv, Wp, xb, wqkv, wpb);
    qkv_gemm<256><<<256, 512, 0, stream>>>(xb, wqkv, bq, bk, bv, qbuf, kbuf, vtb);
    qkv_gemm<128><<<256, 512, 0, stream>>>(xb, wqkv, bq, bk, bv, qbuf, kbuf, vtb);
    attn_kernel<<<512, 512, 0, stream>>>(qbuf, kbuf, vtb, attb);
    proj_gemm<<<512, 256, 0, stream>>>(attb, wpb, bp, (float*)d_out);
}

// Round 17
// 160.808 us; speedup vs baseline: 1.1755x; 1.0173x over previous
//
#include <hip/hip_runtime.h>
#include <stdint.h>

typedef unsigned short u16;
typedef __attribute__((ext_vector_type(8))) __bf16 bf16x8;
typedef __attribute__((ext_vector_type(8))) short short8;
typedef __attribute__((ext_vector_type(4))) float f32x4;
typedef __attribute__((ext_vector_type(16))) float f32x16;
typedef __attribute__((ext_vector_type(4))) uint32_t u32x4;

#define AS1 __attribute__((address_space(1)))
#define AS3 __attribute__((address_space(3)))

__device__ __forceinline__ void load_lds16(const void* g, void* l) {
    __builtin_amdgcn_global_load_lds((AS1 void*)g, (AS3 void*)l, 16, 0, 0);
}

__device__ __forceinline__ u16 f2bf(float f) {
    uint32_t u = __builtin_bit_cast(uint32_t, f);
    u += 0x7FFFu + ((u >> 16) & 1u);
    return (u16)(u >> 16);
}

__device__ __forceinline__ f32x4 mfma16(bf16x8 a, bf16x8 b, f32x4 c) {
    return __builtin_amdgcn_mfma_f32_16x16x32_bf16(a, b, c, 0, 0, 0);
}
__device__ __forceinline__ f32x16 mfma32(bf16x8 a, bf16x8 b, f32x16 c) {
    return __builtin_amdgcn_mfma_f32_32x32x16_bf16(a, b, c, 0, 0, 0);
}

__device__ __forceinline__ float rcpf(float x) {
    float r;
    asm("v_rcp_f32 %0, %1" : "=v"(r) : "v"(x));
    return r;
}

#define CLOG 0.18033688f   /* 0.125 * log2(e) -- folded into Q at qkv epilogue */

#define PHASE_BARRIER()                                                                          \
    {                                                                                            \
        __builtin_amdgcn_sched_barrier(0);                                                       \
        __builtin_amdgcn_s_barrier();                                                            \
    }

// ---------------------------------------------------------------- fused cast f32->bf16
__global__ __launch_bounds__(256) void cast_all(const float* __restrict__ x,
                                                const float* __restrict__ wq,
                                                const float* __restrict__ wk,
                                                const float* __restrict__ wv,
                                                const float* __restrict__ wp,
                                                u16* __restrict__ xb,
                                                u16* __restrict__ wqkv,
                                                u16* __restrict__ wpb) {
    const int bid = blockIdx.x;
    const float* src;
    u16* dst;
    int boff;
    if (bid < 8192)       { src = x;  dst = xb;             boff = bid; }
    else if (bid < 9216)  { src = wq; dst = wqkv;           boff = bid - 8192; }
    else if (bid < 10240) { src = wk; dst = wqkv + 1048576; boff = bid - 9216; }
    else if (bid < 11264) { src = wv; dst = wqkv + 2097152; boff = bid - 10240; }
    else                  { src = wp; dst = wpb;            boff = bid - 11264; }
    const int i = (boff * 256 + threadIdx.x) * 4;
    const float4 v = *(const float4*)(src + i);
    u16 o0 = f2bf(v.x), o1 = f2bf(v.y), o2 = f2bf(v.z), o3 = f2bf(v.w);
    uint32_t lo = (uint32_t)o0 | ((uint32_t)o1 << 16);
    uint32_t hi = (uint32_t)o2 | ((uint32_t)o3 << 16);
    uint2 p; p.x = lo; p.y = hi;
    *(uint2*)(dst + i) = p;
}

// ---------------------------------------------------------------- fused QKV projection
// r16's verified split-grid 8-phase engine (NIA = BM/128).
//   launch 1: BM=256, 256 blocks = tiles nIdx 0..7  (Q+K), 1/CU exact.
//   launch 2: BM=128, 256 blocks = tiles nIdx 8..11 (V) split in M, 1/CU.
template<int BM>
__global__ __launch_bounds__(512) __attribute__((amdgpu_waves_per_eu(2, 2)))
void qkv_gemm(const u16* __restrict__ xb, const u16* __restrict__ wqkv,
              const float* __restrict__ bq, const float* __restrict__ bk,
              const float* __restrict__ bv,
              u16* __restrict__ qo, u16* __restrict__ ko, u16* __restrict__ vt) {
    constexpr int ABUF = BM * 128;           // A bytes per buffer ([BM][128B])
    constexpr int BUFS = ABUF + 32768;       // buffer stride (B region fixed 32KB)
    constexpr int MF = BM / 32;              // acc m-frags per wave (8 / 4)
    constexpr int MH = MF / 2;               // frags per M-half (4 / 2)
    constexpr int NIA = BM / 128;            // A stage issues per half (2 / 1)
    __shared__ char lds[2 * BUFS];
    const int tid = threadIdx.x;
    const int w = tid >> 6, l = tid & 63;
    const int lg = l >> 4, lc = l & 15;
    const int wr = w >> 2, wc = w & 3;       // wave grid 2(M) x 4(N)
    const int id = blockIdx.x;
    const int xcd = id & 7, sl = id >> 3;    // 32 slots/XCD
    int m0, n0;
    if constexpr (BM == 256) {
        const int nIdx = sl >> 2, mloc = sl & 3;     // nIdx 0..7
        m0 = (xcd * 4 + mloc) * 256;
        n0 = nIdx * 256;
    } else {
        const int osl = 32 + (sl >> 1), mh = sl & 1; // original sl 32..47
        const int nIdx = osl >> 2, mloc = osl & 3;   // nIdx 8..11
        m0 = (xcd * 4 + mloc) * 256 + mh * 128;
        n0 = nIdx * 256;
    }

    f32x4 acc[MF][4] = {};                   // wave output (BM/2) x 64

    auto stage_a = [&](int H, int KT, char* BUFP) {
#pragma unroll
        for (int i_ = 0; i_ < NIA; ++i_) {
            const int e_ = i_ * 512 + tid;
            const int row_ = e_ >> 3, c_ = e_ & 7;
            const int cs_ = c_ ^ (row_ & 7);
            load_lds16(xb + (size_t)(m0 + H * (BM / 2) + row_) * 1024 + KT + cs_ * 8,
                       BUFP + H * (ABUF / 2) + i_ * 8192 + w * 1024);
        }
    };
    auto stage_b = [&](int H, int KT, char* BUFP) {
#pragma unroll
        for (int i_ = 0; i_ < 2; ++i_) {
            const int e_ = i_ * 512 + tid;
            const int row_ = e_ >> 3, c_ = e_ & 7;
            const int cs_ = c_ ^ (row_ & 7);
            load_lds16(wqkv + (size_t)(n0 + H * 128 + row_) * 1024 + KT + cs_ * 8,
                       BUFP + ABUF + H * 16384 + i_ * 8192 + w * 1024);
        }
    };

    // ---- prologue: tile0 fully + B halves of tile1
    stage_a(0, 0, lds); stage_a(1, 0, lds);
    stage_b(0, 0, lds); stage_b(1, 0, lds);
    stage_b(0, 64, lds + BUFS); stage_b(1, 64, lds + BUFS);
    asm volatile("s_waitcnt vmcnt(4)" ::: "memory");
    PHASE_BARRIER()

    for (int u = 0; u < 16; ++u) {
        const int kt = u * 64;
        char* cb = lds + (u & 1) * BUFS;
        char* nb = lds + ((u + 1) & 1) * BUFS;
        char* abase = cb + wr * (ABUF / 2);
        char* bbase = cb + ABUF + (wc >> 1) * 16384;
        const int brl = (wc & 1) * 64;
        bf16x8 af[MH][2], bfr[4][2];
        // ---------- P0: quadrant (M0,N0)
#pragma unroll
        for (int m = 0; m < MH; ++m) {
            const int row = m * 16 + lc;
#pragma unroll
            for (int kk = 0; kk < 2; ++kk)
                af[m][kk] = *(const bf16x8*)(abase + row * 128 + ((kk * 64 + lg * 16) ^ ((row & 7) << 4)));
        }
#pragma unroll
        for (int n = 0; n < 2; ++n) {
            const int row = brl + n * 16 + lc;
#pragma unroll
            for (int kk = 0; kk < 2; ++kk)
                bfr[n][kk] = *(const bf16x8*)(bbase + row * 128 + ((kk * 64 + lg * 16) ^ ((row & 7) << 4)));
        }
        if (u < 15) stage_a(0, kt + 64, nb);
        PHASE_BARRIER()
        __builtin_amdgcn_s_setprio(1);
#pragma unroll
        for (int m = 0; m < MH; ++m)
#pragma unroll
            for (int n = 0; n < 2; ++n)
#pragma unroll
                for (int kk = 0; kk < 2; ++kk)
                    acc[m][n] = mfma16(af[m][kk], bfr[n][kk], acc[m][n]);
        __builtin_amdgcn_s_setprio(0);
        PHASE_BARRIER()
        // ---------- P1: quadrant (M0,N1)
#pragma unroll
        for (int n = 2; n < 4; ++n) {
            const int row = brl + n * 16 + lc;
#pragma unroll
            for (int kk = 0; kk < 2; ++kk)
                bfr[n][kk] = *(const bf16x8*)(bbase + row * 128 + ((kk * 64 + lg * 16) ^ ((row & 7) << 4)));
        }
        if (u < 15) stage_a(1, kt + 64, nb);
        PHASE_BARRIER()
        __builtin_amdgcn_s_setprio(1);
#pragma unroll
        for (int m = 0; m < MH; ++m)
#pragma unroll
            for (int n = 2; n < 4; ++n)
#pragma unroll
                for (int kk = 0; kk < 2; ++kk)
                    acc[m][n] = mfma16(af[m][kk], bfr[n][kk], acc[m][n]);
        __builtin_amdgcn_s_setprio(0);
        PHASE_BARRIER()
        // ---------- P2: quadrant (M1,N0) -- B LDS dead; stage B0(u+2) into cb
#pragma unroll
        for (int m = 0; m < MH; ++m) {
            const int row = (BM / 4) + m * 16 + lc;
#pragma unroll
            for (int kk = 0; kk < 2; ++kk)
                af[m][kk] = *(const bf16x8*)(abase + row * 128 + ((kk * 64 + lg * 16) ^ ((row & 7) << 4)));
        }
        if (u < 14) stage_b(0, kt + 128, cb);
        PHASE_BARRIER()
        __builtin_amdgcn_s_setprio(1);
#pragma unroll
        for (int m = 0; m < MH; ++m)
#pragma unroll
            for (int n = 0; n < 2; ++n)
#pragma unroll
                for (int kk = 0; kk < 2; ++kk)
                    acc[MH + m][n] = mfma16(af[m][kk], bfr[n][kk], acc[MH + m][n]);
        __builtin_amdgcn_s_setprio(0);
        PHASE_BARRIER()
        // ---------- P3: quadrant (M1,N1) -- no reads; stage B1(u+2); vmcnt gate
        if (u < 14) stage_b(1, kt + 128, cb);
        PHASE_BARRIER()
        __builtin_amdgcn_s_setprio(1);
#pragma unroll
        for (int m = 0; m < MH; ++m)
#pragma unroll
            for (int n = 2; n < 4; ++n)
#pragma unroll
                for (int kk = 0; kk < 2; ++kk)
                    acc[MH + m][n] = mfma16(af[m][kk], bfr[n][kk], acc[MH + m][n]);
        __builtin_amdgcn_s_setprio(0);
        if (u >= 14) { asm volatile("s_waitcnt vmcnt(0)" ::: "memory"); }
        else         { asm volatile("s_waitcnt vmcnt(4)" ::: "memory"); }
        PHASE_BARRIER()
    }

    // ---- epilogue: bias (+ CLOG fold for Q), scatter to (B,H,T,D)/(B,H,D,T)
    const int ngw = n0 + wc * 64;
    const int whichw = ngw >> 10;                // wave-uniform
    const float* bias = whichw == 0 ? bq : (whichw == 1 ? bk : bv);
    if (whichw == 2) {
#pragma unroll
        for (int mi = 0; mi < MF; ++mi)
#pragma unroll
            for (int ni = 0; ni < 4; ++ni) {
                const int ng = ngw + ni * 16 + lc;
                const int c = ng & 1023;
                const int h = c >> 6, d = c & 63;
                const float bb = bias[c];
                const int t0 = m0 + wr * (BM / 2) + mi * 16 + lg * 4;
                const int b = t0 >> 11, t = t0 & 2047;
                uint32_t w0 = (uint32_t)f2bf(acc[mi][ni][0] + bb) | ((uint32_t)f2bf(acc[mi][ni][1] + bb) << 16);
                uint32_t w1 = (uint32_t)f2bf(acc[mi][ni][2] + bb) | ((uint32_t)f2bf(acc[mi][ni][3] + bb) << 16);
                uint2 pk; pk.x = w0; pk.y = w1;
                *(uint2*)(vt + (((size_t)(b * 16 + h)) * 64 + d) * 2048 + t) = pk;
            }
    } else {
        u16* outb = whichw == 0 ? qo : ko;
        const float sc = whichw == 0 ? CLOG : 1.0f;
#pragma unroll
        for (int mi = 0; mi < MF; ++mi)
#pragma unroll
            for (int ni = 0; ni < 4; ++ni)
#pragma unroll
                for (int r = 0; r < 4; ++r) {
                    const int m = m0 + wr * (BM / 2) + mi * 16 + lg * 4 + r;
                    const int ng = ngw + ni * 16 + lc;
                    const int c = ng & 1023;
                    const float v = (acc[mi][ni][r] + bias[c]) * sc;
                    const int h = c >> 6, d = c & 63;
                    const int b = m >> 11, t = m & 2047;
                    outb[(((size_t)(b * 16 + h)) * 2048 + t) * 64 + d] = f2bf(v);
                }
    }
}

// ---------------------------------------------------------------- output projection
// r17: the r16-verified BM=128 8-phase engine, fp32 epilogue. M=8192 N=1024
// with 128x256 tiles -> 64x4 = 256 blocks = EXACTLY 1/CU, single round (the
// old gemm_core proj ran the m97 2-barrier structure at ~912 TF).
__global__ __launch_bounds__(512) __attribute__((amdgpu_waves_per_eu(2, 2)))
void proj_gemm8(const u16* __restrict__ attb, const u16* __restrict__ wpb,
                const float* __restrict__ bp, float* __restrict__ out) {
    constexpr int ABUF = 16384;              // A bytes per buffer ([128][128B])
    constexpr int BUFS = ABUF + 32768;       // 48KB buffer stride
    __shared__ char lds[2 * BUFS];
    const int tid = threadIdx.x;
    const int w = tid >> 6, l = tid & 63;
    const int lg = l >> 4, lc = l & 15;
    const int wr = w >> 2, wc = w & 3;       // wave grid 2(M of 64) x 4(N of 64)
    const int id = blockIdx.x;
    const int xcd = id & 7, sl = id >> 3;    // 32 slots/XCD
    const int nIdx = sl >> 3, mhalf = sl & 7;
    const int m0 = xcd * 1024 + mhalf * 128;
    const int n0 = nIdx * 256;

    f32x4 acc[4][4] = {};                    // wave output 64 x 64

    auto stage_a = [&](int H, int KT, char* BUFP) {
        const int row_ = tid >> 3, c_ = tid & 7;
        const int cs_ = c_ ^ (row_ & 7);
        load_lds16(attb + (size_t)(m0 + H * 64 + row_) * 1024 + KT + cs_ * 8,
                   BUFP + H * 8192 + w * 1024);
    };
    auto stage_b = [&](int H, int KT, char* BUFP) {
#pragma unroll
        for (int i_ = 0; i_ < 2; ++i_) {
            const int e_ = i_ * 512 + tid;
            const int row_ = e_ >> 3, c_ = e_ & 7;
            const int cs_ = c_ ^ (row_ & 7);
            load_lds16(wpb + (size_t)(n0 + H * 128 + row_) * 1024 + KT + cs_ * 8,
                       BUFP + ABUF + H * 16384 + i_ * 8192 + w * 1024);
        }
    };

    stage_a(0, 0, lds); stage_a(1, 0, lds);
    stage_b(0, 0, lds); stage_b(1, 0, lds);
    stage_b(0, 64, lds + BUFS); stage_b(1, 64, lds + BUFS);
    asm volatile("s_waitcnt vmcnt(4)" ::: "memory");
    PHASE_BARRIER()

    for (int u = 0; u < 16; ++u) {
        const int kt = u * 64;
        char* cb = lds + (u & 1) * BUFS;
        char* nb = lds + ((u + 1) & 1) * BUFS;
        char* abase = cb + wr * 8192;
        char* bbase = cb + ABUF + (wc >> 1) * 16384;
        const int brl = (wc & 1) * 64;
        bf16x8 af[2][2], bfr[4][2];
        // ---------- P0
#pragma unroll
        for (int m = 0; m < 2; ++m) {
            const int row = m * 16 + lc;
#pragma unroll
            for (int kk = 0; kk < 2; ++kk)
                af[m][kk] = *(const bf16x8*)(abase + row * 128 + ((kk * 64 + lg * 16) ^ ((row & 7) << 4)));
        }
#pragma unroll
        for (int n = 0; n < 2; ++n) {
            const int row = brl + n * 16 + lc;
#pragma unroll
            for (int kk = 0; kk < 2; ++kk)
                bfr[n][kk] = *(const bf16x8*)(bbase + row * 128 + ((kk * 64 + lg * 16) ^ ((row & 7) << 4)));
        }
        if (u < 15) stage_a(0, kt + 64, nb);
        PHASE_BARRIER()
        __builtin_amdgcn_s_setprio(1);
#pragma unroll
        for (int m = 0; m < 2; ++m)
#pragma unroll
            for (int n = 0; n < 2; ++n)
#pragma unroll
                for (int kk = 0; kk < 2; ++kk)
                    acc[m][n] = mfma16(af[m][kk], bfr[n][kk], acc[m][n]);
        __builtin_amdgcn_s_setprio(0);
        PHASE_BARRIER()
        // ---------- P1
#pragma unroll
        for (int n = 2; n < 4; ++n) {
            const int row = brl + n * 16 + lc;
#pragma unroll
            for (int kk = 0; kk < 2; ++kk)
                bfr[n][kk] = *(const bf16x8*)(bbase + row * 128 + ((kk * 64 + lg * 16) ^ ((row & 7) << 4)));
        }
        if (u < 15) stage_a(1, kt + 64, nb);
        PHASE_BARRIER()
        __builtin_amdgcn_s_setprio(1);
#pragma unroll
        for (int m = 0; m < 2; ++m)
#pragma unroll
            for (int n = 2; n < 4; ++n)
#pragma unroll
                for (int kk = 0; kk < 2; ++kk)
                    acc[m][n] = mfma16(af[m][kk], bfr[n][kk], acc[m][n]);
        __builtin_amdgcn_s_setprio(0);
        PHASE_BARRIER()
        // ---------- P2
#pragma unroll
        for (int m = 0; m < 2; ++m) {
            const int row = 32 + m * 16 + lc;
#pragma unroll
            for (int kk = 0; kk < 2; ++kk)
                af[m][kk] = *(const bf16x8*)(abase + row * 128 + ((kk * 64 + lg * 16) ^ ((row & 7) << 4)));
        }
        if (u < 14) stage_b(0, kt + 128, cb);
        PHASE_BARRIER()
        __builtin_amdgcn_s_setprio(1);
#pragma unroll
        for (int m = 0; m < 2; ++m)
#pragma unroll
            for (int n = 0; n < 2; ++n)
#pragma unroll
                for (int kk = 0; kk < 2; ++kk)
                    acc[2 + m][n] = mfma16(af[m][kk], bfr[n][kk], acc[2 + m][n]);
        __builtin_amdgcn_s_setprio(0);
        PHASE_BARRIER()
        // ---------- P3
        if (u < 14) stage_b(1, kt + 128, cb);
        PHASE_BARRIER()
        __builtin_amdgcn_s_setprio(1);
#pragma unroll
        for (int m = 0; m < 2; ++m)
#pragma unroll
            for (int n = 2; n < 4; ++n)
#pragma unroll
                for (int kk = 0; kk < 2; ++kk)
                    acc[2 + m][n] = mfma16(af[m][kk], bfr[n][kk], acc[2 + m][n]);
        __builtin_amdgcn_s_setprio(0);
        if (u >= 14) { asm volatile("s_waitcnt vmcnt(0)" ::: "memory"); }
        else         { asm volatile("s_waitcnt vmcnt(4)" ::: "memory"); }
        PHASE_BARRIER()
    }

    // ---- epilogue: fp32 out + bias, coalesced dword runs
#pragma unroll
    for (int mi = 0; mi < 4; ++mi)
#pragma unroll
        for (int ni = 0; ni < 4; ++ni)
#pragma unroll
            for (int r = 0; r < 4; ++r) {
                const int m = m0 + wr * 64 + mi * 16 + lg * 4 + r;
                const int n = n0 + wc * 64 + ni * 16 + lc;
                out[(size_t)m * 1024 + n] = acc[mi][ni][r] + bp[n];
            }
}

// ---------------------------------------------------------------- flash attention (causal)
// r12 version EXACTLY (best measured: 80.1us; counters reconfirmed r14/r16).
__global__ __launch_bounds__(512) __attribute__((amdgpu_waves_per_eu(4, 4)))
void attn_kernel(const u16* __restrict__ qbuf, const u16* __restrict__ kbuf,
                 const u16* __restrict__ vtb, u16* __restrict__ attb) {
    __shared__ char lds[32768];  // [parity][ K 8KB | Vt 8KB ]
    const int tid = threadIdx.x;
    const int w = tid >> 6, l = tid & 63;        // w 0..7
    const int l31 = l & 31, hi = l >> 5;
    const int id = blockIdx.x;
    const int xcd = id & 7, slot = id >> 3;      // slot 0..63 per XCD
    const int round = slot >> 5, k5 = slot & 31;
    const int p = round ? (7 - (k5 & 7)) : (k5 & 7);   // CU pair (p,7-p): rounds sum 50
    const int bh = xcd * 8 + round * 4 + (k5 >> 3);    // 8 heads/XCD (4 per round)
    const int ws = p + (w >> 2) * 8;             // wave's strip: sA=p or sB=p+8
    const size_t base = (size_t)bh * 2048 * 64;  // same stride for (B,H,T,D)/(B,H,D,T)
    const int qw0 = ws * 128 + (w & 3) * 32;     // this wave's 32 q rows
    const int jmax = (qw0 + 31) >> 6;            // last KV tile this wave needs
    const int tH = 2 * p + 18;                   // tiles staged (covers sB=p+8)
    const int qg = qw0 + l31;

    bf16x8 aqf[4];
#pragma unroll
    for (int t = 0; t < 4; ++t)
        aqf[t] = *(const bf16x8*)(qbuf + base + (size_t)(qw0 + l31) * 64 + t * 16 + hi * 8);

    f32x16 oacc[2];
#pragma unroll
    for (int i = 0; i < 16; ++i) { oacc[0][i] = 0.f; oacc[1][i] = 0.f; }
    float lrun = 0.f;   // OWN-HALF unnormalized sums (cross-half add deferred)

#define ISSUE_K(J, BUF)                                                                          \
    {                                                                                            \
        const int row = tid >> 3, c = tid & 7;                                                   \
        const int cs = c ^ (row & 7);                                                            \
        load_lds16(kbuf + base + (size_t)((J) * 64 + row) * 64 + cs * 8, (BUF) + w * 1024);      \
    }
#define ISSUE_VT(J, BUF)                                                                         \
    {                                                                                            \
        const int row = tid >> 3, c = tid & 7;                                                   \
        const int cs = c ^ (row & 7);                                                            \
        load_lds16(vtb + base + (size_t)row * 2048 + (J) * 64 + cs * 8, (BUF) + w * 1024);       \
    }

#define PVSTEP(W, KL, KS)                                                       \
    {                                                                           \
        const uint32_t wa = W[4 * (KL) + 0], wb_ = W[4 * (KL) + 1];             \
        const uint32_t wc = W[4 * (KL) + 2], wd = W[4 * (KL) + 3];              \
        const uint32_t xa = (uint32_t)__shfl_xor((int)wa, 32, 64);              \
        const uint32_t xb = (uint32_t)__shfl_xor((int)wb_, 32, 64);             \
        const uint32_t xc = (uint32_t)__shfl_xor((int)wc, 32, 64);              \
        const uint32_t xd = (uint32_t)__shfl_xor((int)wd, 32, 64);              \
        u32x4 pw;                                                               \
        pw[0] = hi ? xc : wa;                                                   \
        pw[1] = hi ? xd : wb_;                                                  \
        pw[2] = hi ? wc : xa;                                                   \
        pw[3] = hi ? wd : xb;                                                   \
        const bf16x8 paf = __builtin_bit_cast(bf16x8, pw);                      \
        __builtin_amdgcn_s_setprio(1);                                          \
        _Pragma("unroll")                                                       \
        for (int nb = 0; nb < 2; ++nb) {                                        \
            const int vrow = nb * 32 + l31;                                     \
            const bf16x8 bvf = *(const bf16x8*)(Vt + vrow * 128 +               \
                (((KS) * 32 + hi * 16) ^ ((vrow & 7) << 4)));                   \
            oacc[nb] = mfma32(paf, bvf, oacc[nb]);                              \
        }                                                                       \
        __builtin_amdgcn_s_setprio(0);                                          \
    }

#define SOFTMAX_PACK(SF, WV)                                                    \
    {                                                                           \
        float ps[8];                                                            \
        _Pragma("unroll")                                                       \
        for (int i = 0; i < 8; ++i) {                                           \
            const float p0 = exp2f((SF)[2 * i]);                                \
            const float p1 = exp2f((SF)[2 * i + 1]);                            \
            (SF)[2 * i] = p0;                                                   \
            (SF)[2 * i + 1] = p1;                                               \
            ps[i] = p0 + p1;                                                    \
        }                                                                       \
        lrun += ((ps[0] + ps[1]) + (ps[2] + ps[3])) +                           \
                ((ps[4] + ps[5]) + (ps[6] + ps[7]));                            \
        _Pragma("unroll")                                                       \
        for (int i = 0; i < 8; ++i) {                                           \
            uint32_t ww;                                                        \
            asm("v_cvt_pk_bf16_f32 %0, %1, %2"                                  \
                : "=v"(ww) : "v"((SF)[2 * i]), "v"((SF)[2 * i + 1]));           \
            (WV)[i] = ww;                                                       \
        }                                                                       \
    }

    ISSUE_K(0, lds);
    ISSUE_VT(0, lds + 8192);
    for (int j = 0; j < tH; ++j) {
        __syncthreads();
        if (j + 1 < tH) {
            char* nb2 = lds + ((j + 1) & 1) * 16384;
            ISSUE_K(j + 1, nb2);
            ISSUE_VT(j + 1, nb2 + 8192);
        }
        if (j <= jmax) {
            char* Ks = lds + (j & 1) * 16384;
            char* Vt = Ks + 8192;
            const bool two = (qw0 >= j * 64 + 32);   // wave-uniform
            f32x16 sf0, sf1;
#pragma unroll
            for (int i = 0; i < 16; ++i) sf0[i] = 0.f;
            __builtin_amdgcn_s_setprio(1);
#pragma unroll
            for (int t = 0; t < 4; ++t) {
                const bf16x8 ak = *(const bf16x8*)(Ks + l31 * 128 + ((t * 32 + hi * 16) ^ ((l31 & 7) << 4)));
                sf0 = mfma32(ak, aqf[t], sf0);
            }
            __builtin_amdgcn_s_setprio(0);
            if (two) {
#pragma unroll
                for (int i = 0; i < 16; ++i) sf1[i] = 0.f;
                __builtin_amdgcn_s_setprio(1);
#pragma unroll
                for (int t = 0; t < 4; ++t) {
                    const int row = 32 + l31;
                    const bf16x8 ak = *(const bf16x8*)(Ks + row * 128 + ((t * 32 + hi * 16) ^ ((row & 7) << 4)));
                    sf1 = mfma32(ak, aqf[t], sf1);
                }
                __builtin_amdgcn_s_setprio(0);
                if (qw0 == j * 64 + 32) {
#pragma unroll
                    for (int rg = 0; rg < 16; ++rg) {
                        const int ss = j * 64 + 32 + (rg & 3) + 8 * (rg >> 2) + 4 * hi;
                        if (ss > qg) sf1[rg] = -3.0e38f;
                    }
                }
            } else {
#pragma unroll
                for (int rg = 0; rg < 16; ++rg) {
                    const int ss = j * 64 + (rg & 3) + 8 * (rg >> 2) + 4 * hi;
                    if (ss > qg) sf0[rg] = -3.0e38f;
                }
            }
            uint32_t wv[8];
            SOFTMAX_PACK(sf0, wv)
            PVSTEP(wv, 0, 0)
            PVSTEP(wv, 1, 1)
            if (two) {
                SOFTMAX_PACK(sf1, wv)
                PVSTEP(wv, 0, 2)
                PVSTEP(wv, 1, 3)
            }
        }
    }
    // ---- epilogue: cross-half lrun, normalize (v_rcp), write (B,T,C) bf16
    const int b = bh >> 4, h = bh & 15;
    const float lfull = lrun + __shfl_xor(lrun, 32, 64);
    const float inv = rcpf(lfull);
#pragma unroll
    for (int rq = 0; rq < 4; ++rq)
#pragma unroll
        for (int rr = 0; rr < 4; ++rr) {
            const int q = rr + 8 * rq + 4 * hi;
            const float iv = __shfl(inv, q | (l & 32), 64);
            const int t = qw0 + q;
#pragma unroll
            for (int nb = 0; nb < 2; ++nb) {
                const int c = h * 64 + nb * 32 + l31;
                attb[((size_t)(b * 2048 + t)) * 1024 + c] = f2bf(oacc[nb][rq * 4 + rr] * iv);
            }
        }
}

// ---------------------------------------------------------------- launch
extern "C" void kernel_launch(void* const* d_in, const int* in_sizes, int n_in,
                              void* d_out, int out_size, void* d_ws, size_t ws_size,
                              hipStream_t stream) {
    const float* x  = (const float*)d_in[0];
    const float* Wk = (const float*)d_in[1];
    const float* bk = (const float*)d_in[2];
    const float* Wq = (const float*)d_in[3];
    const float* bq = (const float*)d_in[4];
    const float* Wv = (const float*)d_in[5];
    const float* bv = (const float*)d_in[6];
    const float* Wp = (const float*)d_in[7];
    const float* bp = (const float*)d_in[8];
    char* ws = (char*)d_ws;
    u16* xb   = (u16*)(ws);
    u16* wqkv = (u16*)(ws + 16777216);
    u16* wpb  = (u16*)(ws + 23068672);
    u16* qbuf = (u16*)(ws + 25165824);
    u16* kbuf = (u16*)(ws + 41943040);
    u16* vtb  = (u16*)(ws + 58720256);   // (B,H,D,T) pre-transposed V
    u16* attb = (u16*)(ws + 75497472);

    cast_all<<<12288, 256, 0, stream>>>(x, Wq, Wk, Wv, Wp, xb, wqkv, wpb);
    qkv_gemm<256><<<256, 512, 0, stream>>>(xb, wqkv, bq, bk, bv, qbuf, kbuf, vtb);
    qkv_gemm<128><<<256, 512, 0, stream>>>(xb, wqkv, bq, bk, bv, qbuf, kbuf, vtb);
    attn_kernel<<<512, 512, 0, stream>>>(qbuf, kbuf, vtb, attb);
    proj_gemm8<<<256, 512, 0, stream>>>(attb, wpb, bp, (float*)d_out);
}

// Round 18
// 156.887 us; speedup vs baseline: 1.2049x; 1.0250x over previous
//
#include <hip/hip_runtime.h>
#include <stdint.h>

typedef unsigned short u16;
typedef __attribute__((ext_vector_type(8))) __bf16 bf16x8;
typedef __attribute__((ext_vector_type(8))) short short8;
typedef __attribute__((ext_vector_type(4))) float f32x4;
typedef __attribute__((ext_vector_type(16))) float f32x16;
typedef __attribute__((ext_vector_type(4))) uint32_t u32x4;

#define AS1 __attribute__((address_space(1)))
#define AS3 __attribute__((address_space(3)))

__device__ __forceinline__ void load_lds16(const void* g, void* l) {
    __builtin_amdgcn_global_load_lds((AS1 void*)g, (AS3 void*)l, 16, 0, 0);
}

__device__ __forceinline__ u16 f2bf(float f) {
    uint32_t u = __builtin_bit_cast(uint32_t, f);
    u += 0x7FFFu + ((u >> 16) & 1u);
    return (u16)(u >> 16);
}

__device__ __forceinline__ f32x4 mfma16(bf16x8 a, bf16x8 b, f32x4 c) {
    return __builtin_amdgcn_mfma_f32_16x16x32_bf16(a, b, c, 0, 0, 0);
}
__device__ __forceinline__ f32x16 mfma32(bf16x8 a, bf16x8 b, f32x16 c) {
    return __builtin_amdgcn_mfma_f32_32x32x16_bf16(a, b, c, 0, 0, 0);
}

__device__ __forceinline__ float rcpf(float x) {
    float r;
    asm("v_rcp_f32 %0, %1" : "=v"(r) : "v"(x));
    return r;
}

#define CLOG 0.18033688f   /* 0.125 * log2(e) -- folded into Q at qkv epilogue */

#define PHASE_BARRIER()                                                                          \
    {                                                                                            \
        __builtin_amdgcn_sched_barrier(0);                                                       \
        __builtin_amdgcn_s_barrier();                                                            \
    }

// ---------------------------------------------------------------- fused cast f32->bf16
__global__ __launch_bounds__(256) void cast_all(const float* __restrict__ x,
                                                const float* __restrict__ wq,
                                                const float* __restrict__ wk,
                                                const float* __restrict__ wv,
                                                const float* __restrict__ wp,
                                                u16* __restrict__ xb,
                                                u16* __restrict__ wqkv,
                                                u16* __restrict__ wpb) {
    const int bid = blockIdx.x;
    const float* src;
    u16* dst;
    int boff;
    if (bid < 8192)       { src = x;  dst = xb;             boff = bid; }
    else if (bid < 9216)  { src = wq; dst = wqkv;           boff = bid - 8192; }
    else if (bid < 10240) { src = wk; dst = wqkv + 1048576; boff = bid - 9216; }
    else if (bid < 11264) { src = wv; dst = wqkv + 2097152; boff = bid - 10240; }
    else                  { src = wp; dst = wpb;            boff = bid - 11264; }
    const int i = (boff * 256 + threadIdx.x) * 4;
    const float4 v = *(const float4*)(src + i);
    u16 o0 = f2bf(v.x), o1 = f2bf(v.y), o2 = f2bf(v.z), o3 = f2bf(v.w);
    uint32_t lo = (uint32_t)o0 | ((uint32_t)o1 << 16);
    uint32_t hi = (uint32_t)o2 | ((uint32_t)o3 << 16);
    uint2 p; p.x = lo; p.y = hi;
    *(uint2*)(dst + i) = p;
}

// ---------------------------------------------------------------- fused QKV projection
// r18: the r16-verified split-grid engine bodies FUSED into one 512-block
// launch. Blocks 0..255 run BM=256 (Q+K, nIdx 0..7); blocks 256..511 run
// BM=128 (V, nIdx 8..11 split in M). Dispatch order gives per-CU LPT: a CU
// starts its V block the moment ITS Q+K block retires -- the launch-boundary
// global barrier (all-CU straggler wait) and the dispatch gap are removed.
// Bodies are byte-identical to r16 (LDS passed as pointer).
template<int BM>
__device__ __forceinline__ void qkv_body(int id, char* lds,
                                         const u16* __restrict__ xb, const u16* __restrict__ wqkv,
                                         const float* __restrict__ bq, const float* __restrict__ bk,
                                         const float* __restrict__ bv,
                                         u16* __restrict__ qo, u16* __restrict__ ko, u16* __restrict__ vt) {
    constexpr int ABUF = BM * 128;           // A bytes per buffer ([BM][128B])
    constexpr int BUFS = ABUF + 32768;       // buffer stride (B region fixed 32KB)
    constexpr int MF = BM / 32;              // acc m-frags per wave (8 / 4)
    constexpr int MH = MF / 2;               // frags per M-half (4 / 2)
    constexpr int NIA = BM / 128;            // A stage issues per half (2 / 1)
    const int tid = threadIdx.x;
    const int w = tid >> 6, l = tid & 63;
    const int lg = l >> 4, lc = l & 15;
    const int wr = w >> 2, wc = w & 3;       // wave grid 2(M) x 4(N)
    const int xcd = id & 7, sl = id >> 3;    // 32 slots/XCD
    int m0, n0;
    if constexpr (BM == 256) {
        const int nIdx = sl >> 2, mloc = sl & 3;     // nIdx 0..7
        m0 = (xcd * 4 + mloc) * 256;
        n0 = nIdx * 256;
    } else {
        const int osl = 32 + (sl >> 1), mh = sl & 1; // original sl 32..47
        const int nIdx = osl >> 2, mloc = osl & 3;   // nIdx 8..11
        m0 = (xcd * 4 + mloc) * 256 + mh * 128;
        n0 = nIdx * 256;
    }

    f32x4 acc[MF][4] = {};                   // wave output (BM/2) x 64

    auto stage_a = [&](int H, int KT, char* BUFP) {
#pragma unroll
        for (int i_ = 0; i_ < NIA; ++i_) {
            const int e_ = i_ * 512 + tid;
            const int row_ = e_ >> 3, c_ = e_ & 7;
            const int cs_ = c_ ^ (row_ & 7);
            load_lds16(xb + (size_t)(m0 + H * (BM / 2) + row_) * 1024 + KT + cs_ * 8,
                       BUFP + H * (ABUF / 2) + i_ * 8192 + w * 1024);
        }
    };
    auto stage_b = [&](int H, int KT, char* BUFP) {
#pragma unroll
        for (int i_ = 0; i_ < 2; ++i_) {
            const int e_ = i_ * 512 + tid;
            const int row_ = e_ >> 3, c_ = e_ & 7;
            const int cs_ = c_ ^ (row_ & 7);
            load_lds16(wqkv + (size_t)(n0 + H * 128 + row_) * 1024 + KT + cs_ * 8,
                       BUFP + ABUF + H * 16384 + i_ * 8192 + w * 1024);
        }
    };

    // ---- prologue: tile0 fully + B halves of tile1
    stage_a(0, 0, lds); stage_a(1, 0, lds);
    stage_b(0, 0, lds); stage_b(1, 0, lds);
    stage_b(0, 64, lds + BUFS); stage_b(1, 64, lds + BUFS);
    asm volatile("s_waitcnt vmcnt(4)" ::: "memory");
    PHASE_BARRIER()

    for (int u = 0; u < 16; ++u) {
        const int kt = u * 64;
        char* cb = lds + (u & 1) * BUFS;
        char* nb = lds + ((u + 1) & 1) * BUFS;
        char* abase = cb + wr * (ABUF / 2);
        char* bbase = cb + ABUF + (wc >> 1) * 16384;
        const int brl = (wc & 1) * 64;
        bf16x8 af[MH][2], bfr[4][2];
        // ---------- P0: quadrant (M0,N0)
#pragma unroll
        for (int m = 0; m < MH; ++m) {
            const int row = m * 16 + lc;
#pragma unroll
            for (int kk = 0; kk < 2; ++kk)
                af[m][kk] = *(const bf16x8*)(abase + row * 128 + ((kk * 64 + lg * 16) ^ ((row & 7) << 4)));
        }
#pragma unroll
        for (int n = 0; n < 2; ++n) {
            const int row = brl + n * 16 + lc;
#pragma unroll
            for (int kk = 0; kk < 2; ++kk)
                bfr[n][kk] = *(const bf16x8*)(bbase + row * 128 + ((kk * 64 + lg * 16) ^ ((row & 7) << 4)));
        }
        if (u < 15) stage_a(0, kt + 64, nb);
        PHASE_BARRIER()
        __builtin_amdgcn_s_setprio(1);
#pragma unroll
        for (int m = 0; m < MH; ++m)
#pragma unroll
            for (int n = 0; n < 2; ++n)
#pragma unroll
                for (int kk = 0; kk < 2; ++kk)
                    acc[m][n] = mfma16(af[m][kk], bfr[n][kk], acc[m][n]);
        __builtin_amdgcn_s_setprio(0);
        PHASE_BARRIER()
        // ---------- P1: quadrant (M0,N1)
#pragma unroll
        for (int n = 2; n < 4; ++n) {
            const int row = brl + n * 16 + lc;
#pragma unroll
            for (int kk = 0; kk < 2; ++kk)
                bfr[n][kk] = *(const bf16x8*)(bbase + row * 128 + ((kk * 64 + lg * 16) ^ ((row & 7) << 4)));
        }
        if (u < 15) stage_a(1, kt + 64, nb);
        PHASE_BARRIER()
        __builtin_amdgcn_s_setprio(1);
#pragma unroll
        for (int m = 0; m < MH; ++m)
#pragma unroll
            for (int n = 2; n < 4; ++n)
#pragma unroll
                for (int kk = 0; kk < 2; ++kk)
                    acc[m][n] = mfma16(af[m][kk], bfr[n][kk], acc[m][n]);
        __builtin_amdgcn_s_setprio(0);
        PHASE_BARRIER()
        // ---------- P2: quadrant (M1,N0) -- B LDS dead; stage B0(u+2) into cb
#pragma unroll
        for (int m = 0; m < MH; ++m) {
            const int row = (BM / 4) + m * 16 + lc;
#pragma unroll
            for (int kk = 0; kk < 2; ++kk)
                af[m][kk] = *(const bf16x8*)(abase + row * 128 + ((kk * 64 + lg * 16) ^ ((row & 7) << 4)));
        }
        if (u < 14) stage_b(0, kt + 128, cb);
        PHASE_BARRIER()
        __builtin_amdgcn_s_setprio(1);
#pragma unroll
        for (int m = 0; m < MH; ++m)
#pragma unroll
            for (int n = 0; n < 2; ++n)
#pragma unroll
                for (int kk = 0; kk < 2; ++kk)
                    acc[MH + m][n] = mfma16(af[m][kk], bfr[n][kk], acc[MH + m][n]);
        __builtin_amdgcn_s_setprio(0);
        PHASE_BARRIER()
        // ---------- P3: quadrant (M1,N1) -- no reads; stage B1(u+2); vmcnt gate
        if (u < 14) stage_b(1, kt + 128, cb);
        PHASE_BARRIER()
        __builtin_amdgcn_s_setprio(1);
#pragma unroll
        for (int m = 0; m < MH; ++m)
#pragma unroll
            for (int n = 2; n < 4; ++n)
#pragma unroll
                for (int kk = 0; kk < 2; ++kk)
                    acc[MH + m][n] = mfma16(af[m][kk], bfr[n][kk], acc[MH + m][n]);
        __builtin_amdgcn_s_setprio(0);
        if (u >= 14) { asm volatile("s_waitcnt vmcnt(0)" ::: "memory"); }
        else         { asm volatile("s_waitcnt vmcnt(4)" ::: "memory"); }
        PHASE_BARRIER()
    }

    // ---- epilogue: bias (+ CLOG fold for Q), scatter to (B,H,T,D)/(B,H,D,T)
    const int ngw = n0 + wc * 64;
    const int whichw = ngw >> 10;                // wave-uniform
    const float* bias = whichw == 0 ? bq : (whichw == 1 ? bk : bv);
    if (whichw == 2) {
#pragma unroll
        for (int mi = 0; mi < MF; ++mi)
#pragma unroll
            for (int ni = 0; ni < 4; ++ni) {
                const int ng = ngw + ni * 16 + lc;
                const int c = ng & 1023;
                const int h = c >> 6, d = c & 63;
                const float bb = bias[c];
                const int t0 = m0 + wr * (BM / 2) + mi * 16 + lg * 4;
                const int b = t0 >> 11, t = t0 & 2047;
                uint32_t w0 = (uint32_t)f2bf(acc[mi][ni][0] + bb) | ((uint32_t)f2bf(acc[mi][ni][1] + bb) << 16);
                uint32_t w1 = (uint32_t)f2bf(acc[mi][ni][2] + bb) | ((uint32_t)f2bf(acc[mi][ni][3] + bb) << 16);
                uint2 pk; pk.x = w0; pk.y = w1;
                *(uint2*)(vt + (((size_t)(b * 16 + h)) * 64 + d) * 2048 + t) = pk;
            }
    } else {
        u16* outb = whichw == 0 ? qo : ko;
        const float sc = whichw == 0 ? CLOG : 1.0f;
#pragma unroll
        for (int mi = 0; mi < MF; ++mi)
#pragma unroll
            for (int ni = 0; ni < 4; ++ni)
#pragma unroll
                for (int r = 0; r < 4; ++r) {
                    const int m = m0 + wr * (BM / 2) + mi * 16 + lg * 4 + r;
                    const int ng = ngw + ni * 16 + lc;
                    const int c = ng & 1023;
                    const float v = (acc[mi][ni][r] + bias[c]) * sc;
                    const int h = c >> 6, d = c & 63;
                    const int b = m >> 11, t = m & 2047;
                    outb[(((size_t)(b * 16 + h)) * 2048 + t) * 64 + d] = f2bf(v);
                }
    }
}

__global__ __launch_bounds__(512) __attribute__((amdgpu_waves_per_eu(2, 2)))
void qkv_gemm_all(const u16* __restrict__ xb, const u16* __restrict__ wqkv,
                  const float* __restrict__ bq, const float* __restrict__ bk,
                  const float* __restrict__ bv,
                  u16* __restrict__ qo, u16* __restrict__ ko, u16* __restrict__ vt) {
    __shared__ char lds[131072];   // BM=256 needs 128KB; BM=128 path uses first 96KB
    const int bid = blockIdx.x;
    if (bid < 256) qkv_body<256>(bid,       lds, xb, wqkv, bq, bk, bv, qo, ko, vt);
    else           qkv_body<128>(bid - 256, lds, xb, wqkv, bq, bk, bv, qo, ko, vt);
}

// ---------------------------------------------------------------- output projection
// r17-verified BM=128 8-phase engine, fp32 epilogue. 256 blocks = 1/CU.
__global__ __launch_bounds__(512) __attribute__((amdgpu_waves_per_eu(2, 2)))
void proj_gemm8(const u16* __restrict__ attb, const u16* __restrict__ wpb,
                const float* __restrict__ bp, float* __restrict__ out) {
    constexpr int ABUF = 16384;              // A bytes per buffer ([128][128B])
    constexpr int BUFS = ABUF + 32768;       // 48KB buffer stride
    __shared__ char lds[2 * BUFS];
    const int tid = threadIdx.x;
    const int w = tid >> 6, l = tid & 63;
    const int lg = l >> 4, lc = l & 15;
    const int wr = w >> 2, wc = w & 3;       // wave grid 2(M of 64) x 4(N of 64)
    const int id = blockIdx.x;
    const int xcd = id & 7, sl = id >> 3;    // 32 slots/XCD
    const int nIdx = sl >> 3, mhalf = sl & 7;
    const int m0 = xcd * 1024 + mhalf * 128;
    const int n0 = nIdx * 256;

    f32x4 acc[4][4] = {};                    // wave output 64 x 64

    auto stage_a = [&](int H, int KT, char* BUFP) {
        const int row_ = tid >> 3, c_ = tid & 7;
        const int cs_ = c_ ^ (row_ & 7);
        load_lds16(attb + (size_t)(m0 + H * 64 + row_) * 1024 + KT + cs_ * 8,
                   BUFP + H * 8192 + w * 1024);
    };
    auto stage_b = [&](int H, int KT, char* BUFP) {
#pragma unroll
        for (int i_ = 0; i_ < 2; ++i_) {
            const int e_ = i_ * 512 + tid;
            const int row_ = e_ >> 3, c_ = e_ & 7;
            const int cs_ = c_ ^ (row_ & 7);
            load_lds16(wpb + (size_t)(n0 + H * 128 + row_) * 1024 + KT + cs_ * 8,
                       BUFP + ABUF + H * 16384 + i_ * 8192 + w * 1024);
        }
    };

    stage_a(0, 0, lds); stage_a(1, 0, lds);
    stage_b(0, 0, lds); stage_b(1, 0, lds);
    stage_b(0, 64, lds + BUFS); stage_b(1, 64, lds + BUFS);
    asm volatile("s_waitcnt vmcnt(4)" ::: "memory");
    PHASE_BARRIER()

    for (int u = 0; u < 16; ++u) {
        const int kt = u * 64;
        char* cb = lds + (u & 1) * BUFS;
        char* nb = lds + ((u + 1) & 1) * BUFS;
        char* abase = cb + wr * 8192;
        char* bbase = cb + ABUF + (wc >> 1) * 16384;
        const int brl = (wc & 1) * 64;
        bf16x8 af[2][2], bfr[4][2];
        // ---------- P0
#pragma unroll
        for (int m = 0; m < 2; ++m) {
            const int row = m * 16 + lc;
#pragma unroll
            for (int kk = 0; kk < 2; ++kk)
                af[m][kk] = *(const bf16x8*)(abase + row * 128 + ((kk * 64 + lg * 16) ^ ((row & 7) << 4)));
        }
#pragma unroll
        for (int n = 0; n < 2; ++n) {
            const int row = brl + n * 16 + lc;
#pragma unroll
            for (int kk = 0; kk < 2; ++kk)
                bfr[n][kk] = *(const bf16x8*)(bbase + row * 128 + ((kk * 64 + lg * 16) ^ ((row & 7) << 4)));
        }
        if (u < 15) stage_a(0, kt + 64, nb);
        PHASE_BARRIER()
        __builtin_amdgcn_s_setprio(1);
#pragma unroll
        for (int m = 0; m < 2; ++m)
#pragma unroll
            for (int n = 0; n < 2; ++n)
#pragma unroll
                for (int kk = 0; kk < 2; ++kk)
                    acc[m][n] = mfma16(af[m][kk], bfr[n][kk], acc[m][n]);
        __builtin_amdgcn_s_setprio(0);
        PHASE_BARRIER()
        // ---------- P1
#pragma unroll
        for (int n = 2; n < 4; ++n) {
            const int row = brl + n * 16 + lc;
#pragma unroll
            for (int kk = 0; kk < 2; ++kk)
                bfr[n][kk] = *(const bf16x8*)(bbase + row * 128 + ((kk * 64 + lg * 16) ^ ((row & 7) << 4)));
        }
        if (u < 15) stage_a(1, kt + 64, nb);
        PHASE_BARRIER()
        __builtin_amdgcn_s_setprio(1);
#pragma unroll
        for (int m = 0; m < 2; ++m)
#pragma unroll
            for (int n = 2; n < 4; ++n)
#pragma unroll
                for (int kk = 0; kk < 2; ++kk)
                    acc[m][n] = mfma16(af[m][kk], bfr[n][kk], acc[m][n]);
        __builtin_amdgcn_s_setprio(0);
        PHASE_BARRIER()
        // ---------- P2
#pragma unroll
        for (int m = 0; m < 2; ++m) {
            const int row = 32 + m * 16 + lc;
#pragma unroll
            for (int kk = 0; kk < 2; ++kk)
                af[m][kk] = *(const bf16x8*)(abase + row * 128 + ((kk * 64 + lg * 16) ^ ((row & 7) << 4)));
        }
        if (u < 14) stage_b(0, kt + 128, cb);
        PHASE_BARRIER()
        __builtin_amdgcn_s_setprio(1);
#pragma unroll
        for (int m = 0; m < 2; ++m)
#pragma unroll
            for (int n = 0; n < 2; ++n)
#pragma unroll
                for (int kk = 0; kk < 2; ++kk)
                    acc[2 + m][n] = mfma16(af[m][kk], bfr[n][kk], acc[2 + m][n]);
        __builtin_amdgcn_s_setprio(0);
        PHASE_BARRIER()
        // ---------- P3
        if (u < 14) stage_b(1, kt + 128, cb);
        PHASE_BARRIER()
        __builtin_amdgcn_s_setprio(1);
#pragma unroll
        for (int m = 0; m < 2; ++m)
#pragma unroll
            for (int n = 2; n < 4; ++n)
#pragma unroll
                for (int kk = 0; kk < 2; ++kk)
                    acc[2 + m][n] = mfma16(af[m][kk], bfr[n][kk], acc[2 + m][n]);
        __builtin_amdgcn_s_setprio(0);
        if (u >= 14) { asm volatile("s_waitcnt vmcnt(0)" ::: "memory"); }
        else         { asm volatile("s_waitcnt vmcnt(4)" ::: "memory"); }
        PHASE_BARRIER()
    }

    // ---- epilogue: fp32 out + bias, coalesced dword runs
#pragma unroll
    for (int mi = 0; mi < 4; ++mi)
#pragma unroll
        for (int ni = 0; ni < 4; ++ni)
#pragma unroll
            for (int r = 0; r < 4; ++r) {
                const int m = m0 + wr * 64 + mi * 16 + lg * 4 + r;
                const int n = n0 + wc * 64 + ni * 16 + lc;
                out[(size_t)m * 1024 + n] = acc[mi][ni][r] + bp[n];
            }
}

// ---------------------------------------------------------------- flash attention (causal)
// r12 version EXACTLY (best measured: 80.1us; counters reconfirmed r14/r16/r17).
__global__ __launch_bounds__(512) __attribute__((amdgpu_waves_per_eu(4, 4)))
void attn_kernel(const u16* __restrict__ qbuf, const u16* __restrict__ kbuf,
                 const u16* __restrict__ vtb, u16* __restrict__ attb) {
    __shared__ char lds[32768];  // [parity][ K 8KB | Vt 8KB ]
    const int tid = threadIdx.x;
    const int w = tid >> 6, l = tid & 63;        // w 0..7
    const int l31 = l & 31, hi = l >> 5;
    const int id = blockIdx.x;
    const int xcd = id & 7, slot = id >> 3;      // slot 0..63 per XCD
    const int round = slot >> 5, k5 = slot & 31;
    const int p = round ? (7 - (k5 & 7)) : (k5 & 7);   // CU pair (p,7-p): rounds sum 50
    const int bh = xcd * 8 + round * 4 + (k5 >> 3);    // 8 heads/XCD (4 per round)
    const int ws = p + (w >> 2) * 8;             // wave's strip: sA=p or sB=p+8
    const size_t base = (size_t)bh * 2048 * 64;  // same stride for (B,H,T,D)/(B,H,D,T)
    const int qw0 = ws * 128 + (w & 3) * 32;     // this wave's 32 q rows
    const int jmax = (qw0 + 31) >> 6;            // last KV tile this wave needs
    const int tH = 2 * p + 18;                   // tiles staged (covers sB=p+8)
    const int qg = qw0 + l31;

    bf16x8 aqf[4];
#pragma unroll
    for (int t = 0; t < 4; ++t)
        aqf[t] = *(const bf16x8*)(qbuf + base + (size_t)(qw0 + l31) * 64 + t * 16 + hi * 8);

    f32x16 oacc[2];
#pragma unroll
    for (int i = 0; i < 16; ++i) { oacc[0][i] = 0.f; oacc[1][i] = 0.f; }
    float lrun = 0.f;   // OWN-HALF unnormalized sums (cross-half add deferred)

#define ISSUE_K(J, BUF)                                                                          \
    {                                                                                            \
        const int row = tid >> 3, c = tid & 7;                                                   \
        const int cs = c ^ (row & 7);                                                            \
        load_lds16(kbuf + base + (size_t)((J) * 64 + row) * 64 + cs * 8, (BUF) + w * 1024);      \
    }
#define ISSUE_VT(J, BUF)                                                                         \
    {                                                                                            \
        const int row = tid >> 3, c = tid & 7;                                                   \
        const int cs = c ^ (row & 7);                                                            \
        load_lds16(vtb + base + (size_t)row * 2048 + (J) * 64 + cs * 8, (BUF) + w * 1024);       \
    }

#define PVSTEP(W, KL, KS)                                                       \
    {                                                                           \
        const uint32_t wa = W[4 * (KL) + 0], wb_ = W[4 * (KL) + 1];             \
        const uint32_t wc = W[4 * (KL) + 2], wd = W[4 * (KL) + 3];              \
        const uint32_t xa = (uint32_t)__shfl_xor((int)wa, 32, 64);              \
        const uint32_t xb = (uint32_t)__shfl_xor((int)wb_, 32, 64);             \
        const uint32_t xc = (uint32_t)__shfl_xor((int)wc, 32, 64);              \
        const uint32_t xd = (uint32_t)__shfl_xor((int)wd, 32, 64);              \
        u32x4 pw;                                                               \
        pw[0] = hi ? xc : wa;                                                   \
        pw[1] = hi ? xd : wb_;                                                  \
        pw[2] = hi ? wc : xa;                                                   \
        pw[3] = hi ? wd : xb;                                                   \
        const bf16x8 paf = __builtin_bit_cast(bf16x8, pw);                      \
        __builtin_amdgcn_s_setprio(1);                                          \
        _Pragma("unroll")                                                       \
        for (int nb = 0; nb < 2; ++nb) {                                        \
            const int vrow = nb * 32 + l31;                                     \
            const bf16x8 bvf = *(const bf16x8*)(Vt + vrow * 128 +               \
                (((KS) * 32 + hi * 16) ^ ((vrow & 7) << 4)));                   \
            oacc[nb] = mfma32(paf, bvf, oacc[nb]);                              \
        }                                                                       \
        __builtin_amdgcn_s_setprio(0);                                          \
    }

#define SOFTMAX_PACK(SF, WV)                                                    \
    {                                                                           \
        float ps[8];                                                            \
        _Pragma("unroll")                                                       \
        for (int i = 0; i < 8; ++i) {                                           \
            const float p0 = exp2f((SF)[2 * i]);                                \
            const float p1 = exp2f((SF)[2 * i + 1]);                            \
            (SF)[2 * i] = p0;                                                   \
            (SF)[2 * i + 1] = p1;                                               \
            ps[i] = p0 + p1;                                                    \
        }                                                                       \
        lrun += ((ps[0] + ps[1]) + (ps[2] + ps[3])) +                           \
                ((ps[4] + ps[5]) + (ps[6] + ps[7]));                            \
        _Pragma("unroll")                                                       \
        for (int i = 0; i < 8; ++i) {                                           \
            uint32_t ww;                                                        \
            asm("v_cvt_pk_bf16_f32 %0, %1, %2"                                  \
                : "=v"(ww) : "v"((SF)[2 * i]), "v"((SF)[2 * i + 1]));           \
            (WV)[i] = ww;                                                       \
        }                                                                       \
    }

    ISSUE_K(0, lds);
    ISSUE_VT(0, lds + 8192);
    for (int j = 0; j < tH; ++j) {
        __syncthreads();
        if (j + 1 < tH) {
            char* nb2 = lds + ((j + 1) & 1) * 16384;
            ISSUE_K(j + 1, nb2);
            ISSUE_VT(j + 1, nb2 + 8192);
        }
        if (j <= jmax) {
            char* Ks = lds + (j & 1) * 16384;
            char* Vt = Ks + 8192;
            const bool two = (qw0 >= j * 64 + 32);   // wave-uniform
            f32x16 sf0, sf1;
#pragma unroll
            for (int i = 0; i < 16; ++i) sf0[i] = 0.f;
            __builtin_amdgcn_s_setprio(1);
#pragma unroll
            for (int t = 0; t < 4; ++t) {
                const bf16x8 ak = *(const bf16x8*)(Ks + l31 * 128 + ((t * 32 + hi * 16) ^ ((l31 & 7) << 4)));
                sf0 = mfma32(ak, aqf[t], sf0);
            }
            __builtin_amdgcn_s_setprio(0);
            if (two) {
#pragma unroll
                for (int i = 0; i < 16; ++i) sf1[i] = 0.f;
                __builtin_amdgcn_s_setprio(1);
#pragma unroll
                for (int t = 0; t < 4; ++t) {
                    const int row = 32 + l31;
                    const bf16x8 ak = *(const bf16x8*)(Ks + row * 128 + ((t * 32 + hi * 16) ^ ((row & 7) << 4)));
                    sf1 = mfma32(ak, aqf[t], sf1);
                }
                __builtin_amdgcn_s_setprio(0);
                if (qw0 == j * 64 + 32) {
#pragma unroll
                    for (int rg = 0; rg < 16; ++rg) {
                        const int ss = j * 64 + 32 + (rg & 3) + 8 * (rg >> 2) + 4 * hi;
                        if (ss > qg) sf1[rg] = -3.0e38f;
                    }
                }
            } else {
#pragma unroll
                for (int rg = 0; rg < 16; ++rg) {
                    const int ss = j * 64 + (rg & 3) + 8 * (rg >> 2) + 4 * hi;
                    if (ss > qg) sf0[rg] = -3.0e38f;
                }
            }
            uint32_t wv[8];
            SOFTMAX_PACK(sf0, wv)
            PVSTEP(wv, 0, 0)
            PVSTEP(wv, 1, 1)
            if (two) {
                SOFTMAX_PACK(sf1, wv)
                PVSTEP(wv, 0, 2)
                PVSTEP(wv, 1, 3)
            }
        }
    }
    // ---- epilogue: cross-half lrun, normalize (v_rcp), write (B,T,C) bf16
    const int b = bh >> 4, h = bh & 15;
    const float lfull = lrun + __shfl_xor(lrun, 32, 64);
    const float inv = rcpf(lfull);
#pragma unroll
    for (int rq = 0; rq < 4; ++rq)
#pragma unroll
        for (int rr = 0; rr < 4; ++rr) {
            const int q = rr + 8 * rq + 4 * hi;
            const float iv = __shfl(inv, q | (l & 32), 64);
            const int t = qw0 + q;
#pragma unroll
            for (int nb = 0; nb < 2; ++nb) {
                const int c = h * 64 + nb * 32 + l31;
                attb[((size_t)(b * 2048 + t)) * 1024 + c] = f2bf(oacc[nb][rq * 4 + rr] * iv);
            }
        }
}

// ---------------------------------------------------------------- launch
extern "C" void kernel_launch(void* const* d_in, const int* in_sizes, int n_in,
                              void* d_out, int out_size, void* d_ws, size_t ws_size,
                              hipStream_t stream) {
    const float* x  = (const float*)d_in[0];
    const float* Wk = (const float*)d_in[1];
    const float* bk = (const float*)d_in[2];
    const float* Wq = (const float*)d_in[3];
    const float* bq = (const float*)d_in[4];
    const float* Wv = (const float*)d_in[5];
    const float* bv = (const float*)d_in[6];
    const float* Wp = (const float*)d_in[7];
    const float* bp = (const float*)d_in[8];
    char* ws = (char*)d_ws;
    u16* xb   = (u16*)(ws);
    u16* wqkv = (u16*)(ws + 16777216);
    u16* wpb  = (u16*)(ws + 23068672);
    u16* qbuf = (u16*)(ws + 25165824);
    u16* kbuf = (u16*)(ws + 41943040);
    u16* vtb  = (u16*)(ws + 58720256);   // (B,H,D,T) pre-transposed V
    u16* attb = (u16*)(ws + 75497472);

    cast_all<<<12288, 256, 0, stream>>>(x, Wq, Wk, Wv, Wp, xb, wqkv, wpb);
    qkv_gemm_all<<<512, 512, 0, stream>>>(xb, wqkv, bq, bk, bv, qbuf, kbuf, vtb);
    attn_kernel<<<512, 512, 0, stream>>>(qbuf, kbuf, vtb, attb);
    proj_gemm8<<<256, 512, 0, stream>>>(attb, wpb, bp, (float*)d_out);
}